// Round 1
// 1040.556 us; speedup vs baseline: 1.0195x; 1.0195x over previous
//
#include <hip/hip_runtime.h>
#include <hip/hip_bf16.h>

// TreeLSTM (child-sum, complete binary tree, DEPTH=8) on MI355X.
// Round 5: big GEMMs moved to 256x256/BK=64 8-wave deep-pipelined kernel
// (T1 XCD swizzle + T2 st_16x32 LDS swizzle + T3/T4 counted-vmcnt phase
// schedule + T5 setprio). Leaf re-chunked to 2x8192 rows (C overlays
// A5+Cbuf = exactly 8192*2304*2B). Old 128^2 kernel kept for root/out.

#define Hdim 768

typedef __hip_bfloat16 bf16;
typedef __attribute__((ext_vector_type(8))) short short8;
typedef __attribute__((ext_vector_type(4))) float floatx4;

__device__ inline float b2f(unsigned short u) {
    union { unsigned int i; float f; } v; v.i = ((unsigned int)u) << 16; return v.f;
}
__device__ inline float b2f(bf16 h) { return b2f(*(unsigned short*)&h); }
__device__ inline unsigned short f2bu(float f) {
    bf16 h = __float2bfloat16(f);
    return *(unsigned short*)&h;
}
__device__ inline ushort4 cvt4(float4 v) {
    ushort4 o; o.x = f2bu(v.x); o.y = f2bu(v.y); o.z = f2bu(v.z); o.w = f2bu(v.w);
    return o;
}

// ---------------- weight prep ----------------
// W_cat[l] : [3072][1536] = [[Wioux[l] | Wiouh[l]]; [Wfx[l] | 0]]
__global__ __launch_bounds__(384) void conv_wcat(
    const float* __restrict__ Wioux, const float* __restrict__ Wiouh,
    const float* __restrict__ Wfx, bf16* __restrict__ W_cat)
{
    const int row = blockIdx.x;          // 0 .. 8*3072-1
    const int l = row / 3072;
    const int g = row % 3072;
    const int t = threadIdx.x;
    const int k2 = t << 2;
    float4 v;
    if (g < 2304) {
        const float* src = (k2 < 768)
            ? Wioux + ((long)l * 2304 + g) * 768 + k2
            : Wiouh + ((long)l * 2304 + g) * 768 + (k2 - 768);
        v = *(const float4*)src;
    } else if (k2 < 768) {
        v = *(const float4*)(Wfx + ((long)l * 768 + (g - 2304)) * 768 + k2);
    } else {
        v = make_float4(0.f, 0.f, 0.f, 0.f);
    }
    ((ushort4*)(W_cat + (long)row * 1536))[t] = cvt4(v);
}

// Merged prep: Wfh f2b [0,4608) | Wout f2b [4608,5184) | b_cat [5184,5280)
//            | leaf conv [5280, 5280+16384)
__global__ __launch_bounds__(256) void prep_misc(
    const float* __restrict__ Wfh, const float* __restrict__ Wout,
    const float* __restrict__ b_ioux, const float* __restrict__ b_fx,
    const float* __restrict__ x,
    bf16* __restrict__ Wfh_bf, bf16* __restrict__ Wout_bf,
    float* __restrict__ b_cat, bf16* __restrict__ leafA)
{
    const int id = blockIdx.x;
    const int t = threadIdx.x;
    if (id < 4608) {
        const long i = (long)id * 256 + t;
        ((ushort4*)Wfh_bf)[i] = cvt4(((const float4*)Wfh)[i]);
    } else if (id < 5184) {
        const long i = (long)(id - 4608) * 256 + t;
        ((ushort4*)Wout_bf)[i] = cvt4(((const float4*)Wout)[i]);
    } else if (id < 5280) {
        const int i = (id - 5184) * 256 + t;   // 0..24575
        const int l = i / 3072, g = i % 3072;
        b_cat[i] = (g < 2304) ? b_ioux[l * 2304 + g] : b_fx[l * 768 + (g - 2304)];
    } else if (t < 192) {
        const int m = id - 5280;               // 0..16383
        const int b = m >> 7, j = m & 127;
        const float* xr = x + ((long)b * 255 + 127 + j) * Hdim;
        ((ushort4*)(leafA + (long)m * Hdim))[t] = cvt4(((const float4*)xr)[t]);
    }
}

// ---------------- GEMM descriptors ----------------
struct GemmDesc {
    const bf16* A; int lda;
    const bf16* W; int ldw;
    const float* bias;
    void* C; int ldc; int c_fp32;
    int K; int nxb;                      // n-blocks (N / tile_n of the kernel used)
    const float* addv; long add_stride;
};

static inline GemmDesc mkdesc(const bf16* A, int lda, const bf16* W, int ldw,
                              const float* bias, void* C, int ldc, int c_fp32,
                              int K, int nxb, const float* addv, long add_stride) {
    GemmDesc d; d.A = A; d.lda = lda; d.W = W; d.ldw = ldw; d.bias = bias;
    d.C = C; d.ldc = ldc; d.c_fp32 = c_fp32; d.K = K; d.nxb = nxb;
    d.addv = addv; d.add_stride = add_stride; return d;
}

// ---------------- small MFMA GEMM (root/out only; 128x128, nxb = N/128) ----
__global__ __launch_bounds__(256) void gemm_dual(GemmDesc da, int na, GemmDesc db)
{
    __shared__ __align__(16) bf16 As[128 * 32];
    __shared__ __align__(16) bf16 Ws[128 * 32];
    int id = blockIdx.x;
    const bool second = (id >= na);
    if (second) id -= na;
    const GemmDesc d = second ? db : da;
    const int bm = id / d.nxb, bn = id % d.nxb;

    const int t = threadIdx.x;
    const int wave = t >> 6, lane = t & 63;
    const long m_blk = (long)bm << 7;
    const long n_blk = (long)bn << 7;

    const int srow = (wave << 5) + (lane >> 2);
    const int sbyte = (lane & 3) << 4;
    const char* gA = (const char*)(d.A + (m_blk + srow) * (long)d.lda) + sbyte;
    const char* gW = (const char*)(d.W + (n_blk + srow) * (long)d.ldw) + sbyte;
    const long aRow16 = (long)d.lda * 32;
    const long wRow16 = (long)d.ldw * 32;
    bf16* lA = As + (wave << 10);
    bf16* lW = Ws + (wave << 10);

    floatx4 zero = {0.f, 0.f, 0.f, 0.f};
    floatx4 acc[4][4];
#pragma unroll
    for (int i = 0; i < 4; i++)
#pragma unroll
        for (int j = 0; j < 4; j++) acc[i][j] = zero;

    const int mrow = (wave & 1) << 6;
    const int ncol = (wave >> 1) << 6;
    const short* AsS = (const short*)As;
    const short* WsS = (const short*)Ws;
    const int fm = lane & 15;
    const int fk = (lane >> 4) << 3;

    for (int k0 = 0; k0 < d.K; k0 += 32) {
        __builtin_amdgcn_global_load_lds(
            (const __attribute__((address_space(1))) unsigned int*)gA,
            (__attribute__((address_space(3))) unsigned int*)lA, 16, 0, 0);
        __builtin_amdgcn_global_load_lds(
            (const __attribute__((address_space(1))) unsigned int*)(gA + aRow16),
            (__attribute__((address_space(3))) unsigned int*)(lA + 512), 16, 0, 0);
        __builtin_amdgcn_global_load_lds(
            (const __attribute__((address_space(1))) unsigned int*)gW,
            (__attribute__((address_space(3))) unsigned int*)lW, 16, 0, 0);
        __builtin_amdgcn_global_load_lds(
            (const __attribute__((address_space(1))) unsigned int*)(gW + wRow16),
            (__attribute__((address_space(3))) unsigned int*)(lW + 512), 16, 0, 0);
        gA += 64; gW += 64;
        __syncthreads();

        short8 af[4], bfr[4];
#pragma unroll
        for (int i = 0; i < 4; i++) {
            af[i]  = *(const short8*)(AsS + (mrow + i * 16 + fm) * 32 + fk);
            bfr[i] = *(const short8*)(WsS + (ncol + i * 16 + fm) * 32 + fk);
        }
#pragma unroll
        for (int i = 0; i < 4; i++)
#pragma unroll
            for (int j = 0; j < 4; j++)
                acc[i][j] = __builtin_amdgcn_mfma_f32_16x16x32_bf16(
                    af[i], bfr[j], acc[i][j], 0, 0, 0);
        __syncthreads();
    }

    const int crow0 = (lane >> 4) << 2;
    const int ccol = lane & 15;
#pragma unroll
    for (int i = 0; i < 4; i++) {
#pragma unroll
        for (int j = 0; j < 4; j++) {
            const long col = n_blk + ncol + j * 16 + ccol;
            const float bv = d.bias ? d.bias[col] : 0.f;
#pragma unroll
            for (int r = 0; r < 4; r++) {
                const long row = m_blk + mrow + i * 16 + crow0 + r;
                float v = acc[i][j][r] + bv;
                if (d.addv) v += d.addv[row * d.add_stride + col];
                if (d.c_fp32) ((float*)d.C)[row * (long)d.ldc + col] = v;
                else ((bf16*)d.C)[row * (long)d.ldc + col] = __float2bfloat16(v);
            }
        }
    }
}

// ---------------- big MFMA GEMM: 256x256 tile, BK=64, 8 waves, 8-phase ----
// nxb = N/256; M multiple of 256, K multiple of 64 (>=128).
// Schedule (per K-tile, buffers alternate per tile):
//   P1: ds A[m0-3]x2k (8) + B[n0-1]x2k (4); stage A1(t+1)->buf^1; bar;
//       lgkm0; MFMA q(m0-3,n0-1)
//   P2: ds B[n2-3]x2k (4); bar; lgkm0; MFMA q(m0-3,n2-3)   [B-halves now dead]
//   P3: ds A[m4-7]x2k (8); stage B0(t+2)->buf; bar; lgkm0;
//       MFMA q(m4-7,n2-3)                                   [A-halves now dead]
//   P4: stage B1(t+2),A0(t+2)->buf; MFMA q(m4-7,n0-1);
//       boundary: vmcnt(6) (6 loads of t+2 in flight; vmcnt(0) entering T-1);
//       bar
// Prologue stages t0{A0,A1,B0,B1} + t1{B0,B1,A0} (14 loads), vmcnt(6).
// LDS swizzle st_16x32: byte ^= ((byte>>9)&1)<<5, applied on the pre-swizzled
// global source (write side) and as a per-lane XOR on ds_read (read side).
__global__ __launch_bounds__(512, 2) void gemm8_dual(GemmDesc da, int na, GemmDesc db)
{
    __shared__ __align__(16) char smem[131072];   // A: [2][32K] @0, B @65536

    int id = blockIdx.x;
    int nwg = na;
    bool second = false;
    if (id >= na) { id -= na; nwg = (int)gridDim.x - na; second = true; }
    const GemmDesc d = second ? db : da;
    {   // bijective XCD swizzle (8 XCDs), m204 variant
        const int q = nwg >> 3, r = nwg & 7;
        const int x = id & 7, i2 = id >> 3;
        id = (x < r ? x * (q + 1) : r * (q + 1) + (x - r) * q) + i2;
    }
    const int bm = id / d.nxb, bn = id % d.nxb;
    const int tid = threadIdx.x;
    const int w = tid >> 6, lane = tid & 63;
    const long m_blk = (long)bm << 8;
    const long n_blk = (long)bn << 8;
    const int T = d.K >> 6;                       // K-tiles (>=2 for all users)

    // ---- staging addressing; source pre-swizzled so LDS content is st_16x32.
    // dest byte (tile-local) = half*16384 + w*2048 + i*1024 + lane*16;
    // swz flips bit5 iff lane>=32 -> row = half*128+w*16+i*8+(lane>>3),
    // colb = (lane&7)*16 ^ (lane&32).
    const int colb = ((lane & 7) << 4) ^ (lane & 32);
    const int rw = (w << 4) + (lane >> 3);
    const long ldaB = (long)d.lda * 2, ldwB = (long)d.ldw * 2;
    const char* gA0 = (const char*)(d.A + m_blk * d.lda) + (long)rw * ldaB + colb;
    const char* gB0 = (const char*)(d.W + n_blk * d.ldw) + (long)rw * ldwB + colb;
    const long aH = ldaB << 7, bH = ldwB << 7;    // +128 rows (half 1)
    const long a8 = ldaB << 3, b8 = ldwB << 3;    // +8 rows (second instr)
    char* lW = smem + (w << 11);

    auto stageA = [&](int tile, int buf, int half) {
        const char* g = gA0 + (half ? aH : 0) + ((long)tile << 7);
        char* l = lW + buf * 32768 + half * 16384;
        __builtin_amdgcn_global_load_lds(
            (const __attribute__((address_space(1))) unsigned int*)g,
            (__attribute__((address_space(3))) unsigned int*)l, 16, 0, 0);
        __builtin_amdgcn_global_load_lds(
            (const __attribute__((address_space(1))) unsigned int*)(g + a8),
            (__attribute__((address_space(3))) unsigned int*)(l + 1024), 16, 0, 0);
    };
    auto stageB = [&](int tile, int buf, int half) {
        const char* g = gB0 + (half ? bH : 0) + ((long)tile << 7);
        char* l = lW + 65536 + buf * 32768 + half * 16384;
        __builtin_amdgcn_global_load_lds(
            (const __attribute__((address_space(1))) unsigned int*)g,
            (__attribute__((address_space(3))) unsigned int*)l, 16, 0, 0);
        __builtin_amdgcn_global_load_lds(
            (const __attribute__((address_space(1))) unsigned int*)(g + b8),
            (__attribute__((address_space(3))) unsigned int*)(l + 1024), 16, 0, 0);
    };

    // ---- fragment read addressing: linear byte = row*128 + ks*64 + (lane>>4)*16,
    // row = base + (lane&15); bit9 = row&4 = lane&4 -> per-lane constant XOR.
    const int fm = lane & 15;
    const int fkB = (lane >> 4) << 4;
    const int sx = (lane & 4) << 3;
    const int arow0 = ((w >> 2) << 7) + fm;       // wr*128 + fm
    const int brow0 = ((w & 3) << 6) + fm;        // wc*64 + fm

    floatx4 acc[8][4];
    const floatx4 fzero = {0.f, 0.f, 0.f, 0.f};
#pragma unroll
    for (int i = 0; i < 8; i++)
#pragma unroll
        for (int j = 0; j < 4; j++) acc[i][j] = fzero;

    // ---- prologue ----
    stageA(0, 0, 0); stageA(0, 0, 1); stageB(0, 0, 0); stageB(0, 0, 1);
    if (T > 1) {
        stageB(1, 1, 0); stageB(1, 1, 1); stageA(1, 1, 0);
        asm volatile("s_waitcnt vmcnt(6)" ::: "memory");
    } else {
        asm volatile("s_waitcnt vmcnt(0)" ::: "memory");
    }
    __builtin_amdgcn_sched_barrier(0);
    __builtin_amdgcn_s_barrier();
    __builtin_amdgcn_sched_barrier(0);

    short8 a[4][2], b[4][2];
    for (int tt = 0; tt < T; ++tt) {
        const int buf = tt & 1;
        const char* la = smem + buf * 32768;
        const char* lb = smem + 65536 + buf * 32768;
        // ---------- P1
#pragma unroll
        for (int mf = 0; mf < 4; ++mf)
#pragma unroll
            for (int ks = 0; ks < 2; ++ks)
                a[mf][ks] = *(const short8*)(la + ((((arow0 + mf * 16) << 7) + ks * 64 + fkB) ^ sx));
#pragma unroll
        for (int nf = 0; nf < 2; ++nf)
#pragma unroll
            for (int ks = 0; ks < 2; ++ks)
                b[nf][ks] = *(const short8*)(lb + ((((brow0 + nf * 16) << 7) + ks * 64 + fkB) ^ sx));
        if (tt + 1 < T) stageA(tt + 1, buf ^ 1, 1);
        __builtin_amdgcn_s_barrier();
        asm volatile("s_waitcnt lgkmcnt(0)" ::: "memory");
        __builtin_amdgcn_sched_barrier(0);
        __builtin_amdgcn_s_setprio(1);
#pragma unroll
        for (int ks = 0; ks < 2; ++ks)
#pragma unroll
            for (int mf = 0; mf < 4; ++mf)
#pragma unroll
                for (int nf = 0; nf < 2; ++nf)
                    acc[mf][nf] = __builtin_amdgcn_mfma_f32_16x16x32_bf16(
                        a[mf][ks], b[nf][ks], acc[mf][nf], 0, 0, 0);
        __builtin_amdgcn_s_setprio(0);
        __builtin_amdgcn_s_barrier();
        __builtin_amdgcn_sched_barrier(0);
        // ---------- P2
#pragma unroll
        for (int nf = 0; nf < 2; ++nf)
#pragma unroll
            for (int ks = 0; ks < 2; ++ks)
                b[2 + nf][ks] = *(const short8*)(lb + ((((brow0 + (2 + nf) * 16) << 7) + ks * 64 + fkB) ^ sx));
        __builtin_amdgcn_s_barrier();
        asm volatile("s_waitcnt lgkmcnt(0)" ::: "memory");
        __builtin_amdgcn_sched_barrier(0);
        __builtin_amdgcn_s_setprio(1);
#pragma unroll
        for (int ks = 0; ks < 2; ++ks)
#pragma unroll
            for (int mf = 0; mf < 4; ++mf)
#pragma unroll
                for (int nf = 0; nf < 2; ++nf)
                    acc[mf][2 + nf] = __builtin_amdgcn_mfma_f32_16x16x32_bf16(
                        a[mf][ks], b[2 + nf][ks], acc[mf][2 + nf], 0, 0, 0);
        __builtin_amdgcn_s_setprio(0);
        __builtin_amdgcn_s_barrier();
        __builtin_amdgcn_sched_barrier(0);
        // ---------- P3
#pragma unroll
        for (int mf = 0; mf < 4; ++mf)
#pragma unroll
            for (int ks = 0; ks < 2; ++ks)
                a[mf][ks] = *(const short8*)(la + ((((arow0 + (4 + mf) * 16) << 7) + ks * 64 + fkB) ^ sx));
        if (tt + 2 < T) stageB(tt + 2, buf, 0);
        __builtin_amdgcn_s_barrier();
        asm volatile("s_waitcnt lgkmcnt(0)" ::: "memory");
        __builtin_amdgcn_sched_barrier(0);
        __builtin_amdgcn_s_setprio(1);
#pragma unroll
        for (int ks = 0; ks < 2; ++ks)
#pragma unroll
            for (int mf = 0; mf < 4; ++mf)
#pragma unroll
                for (int nf = 0; nf < 2; ++nf)
                    acc[4 + mf][2 + nf] = __builtin_amdgcn_mfma_f32_16x16x32_bf16(
                        a[mf][ks], b[2 + nf][ks], acc[4 + mf][2 + nf], 0, 0, 0);
        __builtin_amdgcn_s_setprio(0);
        __builtin_amdgcn_s_barrier();
        __builtin_amdgcn_sched_barrier(0);
        // ---------- P4 (no ds reads; stages overlap MFMA)
        if (tt + 2 < T) { stageB(tt + 2, buf, 1); stageA(tt + 2, buf, 0); }
        __builtin_amdgcn_s_setprio(1);
#pragma unroll
        for (int ks = 0; ks < 2; ++ks)
#pragma unroll
            for (int mf = 0; mf < 4; ++mf)
#pragma unroll
                for (int nf = 0; nf < 2; ++nf)
                    acc[4 + mf][nf] = __builtin_amdgcn_mfma_f32_16x16x32_bf16(
                        a[mf][ks], b[nf][ks], acc[4 + mf][nf], 0, 0, 0);
        __builtin_amdgcn_s_setprio(0);
        if (tt + 1 < T) {
            if (tt + 2 < T) asm volatile("s_waitcnt vmcnt(6)" ::: "memory");
            else            asm volatile("s_waitcnt vmcnt(0)" ::: "memory");
            __builtin_amdgcn_sched_barrier(0);
            __builtin_amdgcn_s_barrier();
            __builtin_amdgcn_sched_barrier(0);
        }
    }

    // ---------- epilogue ----------
    const int crow = (lane >> 4) << 2;
    const int ccol = lane & 15;
    const long row0 = m_blk + ((long)(w >> 2) << 7);
    const long col0 = n_blk + ((w & 3) << 6);
#pragma unroll
    for (int mf = 0; mf < 8; ++mf) {
#pragma unroll
        for (int nf = 0; nf < 4; ++nf) {
            const long col = col0 + nf * 16 + ccol;
            const float bv = d.bias ? d.bias[col] : 0.f;
#pragma unroll
            for (int r = 0; r < 4; ++r) {
                const long row = row0 + mf * 16 + crow + r;
                const float v = acc[mf][nf][r] + bv;
                if (d.c_fp32) ((float*)d.C)[row * (long)d.ldc + col] = v;
                else ((bf16*)d.C)[row * (long)d.ldc + col] = __float2bfloat16(v);
            }
        }
    }
}

// ---------------- pointwise ----------------
__device__ inline float sigf(float x) { return 1.f / (1.f + __expf(-x)); }
__device__ inline float tanh_fast(float x) { return 2.f / (1.f + __expf(-2.f * x)) - 1.f; }

__device__ inline void block_reduce4(float& a, float& b, float& c, float& d,
                                     float* s) {
#pragma unroll
    for (int off = 32; off > 0; off >>= 1) {
        a += __shfl_down(a, off, 64);
        b += __shfl_down(b, off, 64);
        c += __shfl_down(c, off, 64);
        d += __shfl_down(d, off, 64);
    }
    const int lane = threadIdx.x & 63, w = threadIdx.x >> 6;
    __syncthreads();
    if (lane == 0) { s[w] = a; s[w + 4] = b; s[w + 8] = c; s[w + 12] = d; }
    __syncthreads();
    a = s[0] + s[1] + s[2] + s[3];
    b = s[4] + s[5] + s[6] + s[7];
    c = s[8] + s[9] + s[10] + s[11];
    d = s[12] + s[13] + s[14] + s[15];
}

// Block handles sibling rows 2p,2p+1 (chunk-local). Writes h rows and the
// next level's A_cat row [xs | h0+h1] at parent index.
__global__ __launch_bounds__(256) void pointwise_pair(
    const bf16* __restrict__ C, int ldc,
    const bf16* __restrict__ fhb,
    const bf16* __restrict__ hprev2,
    const float* __restrict__ x,
    const float* __restrict__ bfh,
    const float* __restrict__ gc, const float* __restrict__ bc,
    const float* __restrict__ gh, const float* __restrict__ bh,
    bf16* __restrict__ hout,
    bf16* __restrict__ Anext,
    int m0, int lp)
{
    __shared__ float sred[16];
    const int pl = blockIdx.x;
    const bf16* cr0 = C + (long)(2 * pl) * ldc;
    const bf16* cr1 = cr0 + ldc;
    float c0v[3], c1v[3], o0v[3], o1v[3], h0v[3], h1v[3];
    float s0 = 0.f, q0 = 0.f, s1 = 0.f, q1 = 0.f;
#pragma unroll
    for (int tI = 0; tI < 3; tI++) {
        const int j = threadIdx.x + tI * 256;
        const float i0 = sigf(b2f(cr0[j]));
        const float i1 = sigf(b2f(cr1[j]));
        o0v[tI] = b2f(cr0[Hdim + j]);
        o1v[tI] = b2f(cr1[Hdim + j]);
        float c0 = i0 * tanh_fast(b2f(cr0[2 * Hdim + j]));
        float c1 = i1 * tanh_fast(b2f(cr1[2 * Hdim + j]));
        if (fhb) {
            const float bfhj = bfh[j];
            const float fx0 = b2f(cr0[3 * Hdim + j]);
            const float fx1 = b2f(cr1[3 * Hdim + j]);
            const long base = (long)(4 * pl) * Hdim + j;
            const float f00 = sigf(fx0 + b2f(fhb[base]) + bfhj);
            const float f01 = sigf(fx0 + b2f(fhb[base + Hdim]) + bfhj);
            const float f10 = sigf(fx1 + b2f(fhb[base + 2 * Hdim]) + bfhj);
            const float f11 = sigf(fx1 + b2f(fhb[base + 3 * Hdim]) + bfhj);
            c0 += f00 * b2f(hprev2[base]) + f01 * b2f(hprev2[base + Hdim]);
            c1 += f10 * b2f(hprev2[base + 2 * Hdim]) + f11 * b2f(hprev2[base + 3 * Hdim]);
        }
        c0v[tI] = c0; c1v[tI] = c1;
        s0 += c0; q0 += c0 * c0; s1 += c1; q1 += c1 * c1;
    }
    block_reduce4(s0, q0, s1, q1, sred);
    const float m0c = s0 / Hdim, m1c = s1 / Hdim;
    const float r0c = rsqrtf(q0 / Hdim - m0c * m0c + 1e-5f);
    const float r1c = rsqrtf(q1 / Hdim - m1c * m1c + 1e-5f);
    float hs0 = 0.f, hq0 = 0.f, hs1 = 0.f, hq1 = 0.f;
#pragma unroll
    for (int tI = 0; tI < 3; tI++) {
        const int j = threadIdx.x + tI * 256;
        const float cn0 = (c0v[tI] - m0c) * r0c * gc[j] + bc[j];
        const float cn1 = (c1v[tI] - m1c) * r1c * gc[j] + bc[j];
        const float h0 = sigf(o0v[tI]) * tanh_fast(cn0);
        const float h1 = sigf(o1v[tI]) * tanh_fast(cn1);
        h0v[tI] = h0; h1v[tI] = h1;
        hs0 += h0; hq0 += h0 * h0; hs1 += h1; hq1 += h1 * h1;
    }
    block_reduce4(hs0, hq0, hs1, hq1, sred);
    const float mh0 = hs0 / Hdim, mh1 = hs1 / Hdim;
    const float rh0 = rsqrtf(hq0 / Hdim - mh0 * mh0 + 1e-5f);
    const float rh1 = rsqrtf(hq1 / Hdim - mh1 * mh1 + 1e-5f);

    const int pg = m0 / 2 + pl;
    const int b = pg >> lp;
    const int jn = pg & ((1 << lp) - 1);
    const float* xr = x + ((long)b * 255 + (1 << lp) - 1 + jn) * Hdim;
    bf16* arow = Anext + (long)pg * 1536;
#pragma unroll
    for (int tI = 0; tI < 3; tI++) {
        const int j = threadIdx.x + tI * 256;
        const float h0 = (h0v[tI] - mh0) * rh0 * gh[j] + bh[j];
        const float h1 = (h1v[tI] - mh1) * rh1 * gh[j] + bh[j];
        hout[(long)(2 * pl) * Hdim + j] = __float2bfloat16(h0);
        hout[(long)(2 * pl + 1) * Hdim + j] = __float2bfloat16(h1);
        arow[768 + j] = __float2bfloat16(h0 + h1);
        arow[j] = __float2bfloat16(xr[j]);
    }
}

__global__ __launch_bounds__(256) void pointwise_root(
    const bf16* __restrict__ C, int ldc,
    const bf16* __restrict__ fhb, const bf16* __restrict__ hprev,
    const float* __restrict__ bfh,
    const float* __restrict__ gc, const float* __restrict__ bc,
    const float* __restrict__ gh, const float* __restrict__ bh,
    bf16* __restrict__ hout)
{
    __shared__ float sred[16];
    const int m = blockIdx.x;
    const bf16* cr = C + (long)m * ldc;
    float cv[3], ov[3], hv[3];
    float ssum = 0.f, ssq = 0.f, d0 = 0.f, d1 = 0.f;
#pragma unroll
    for (int tI = 0; tI < 3; tI++) {
        const int j = threadIdx.x + tI * 256;
        const float i_ = sigf(b2f(cr[j]));
        ov[tI] = b2f(cr[Hdim + j]);
        float c = i_ * tanh_fast(b2f(cr[2 * Hdim + j]));
        const float fx = b2f(cr[3 * Hdim + j]);
        const float bfhj = bfh[j];
        const long base = (long)(2 * m) * Hdim + j;
        const float f0 = sigf(fx + b2f(fhb[base]) + bfhj);
        const float f1 = sigf(fx + b2f(fhb[base + Hdim]) + bfhj);
        c += f0 * b2f(hprev[base]) + f1 * b2f(hprev[base + Hdim]);
        cv[tI] = c; ssum += c; ssq += c * c;
    }
    block_reduce4(ssum, ssq, d0, d1, sred);
    const float mean = ssum / Hdim;
    const float rstd = rsqrtf(ssq / Hdim - mean * mean + 1e-5f);
    float hs = 0.f, hq = 0.f;
#pragma unroll
    for (int tI = 0; tI < 3; tI++) {
        const int j = threadIdx.x + tI * 256;
        const float cn = (cv[tI] - mean) * rstd * gc[j] + bc[j];
        const float h = sigf(ov[tI]) * tanh_fast(cn);
        hv[tI] = h; hs += h; hq += h * h;
    }
    d0 = 0.f; d1 = 0.f;
    block_reduce4(hs, hq, d0, d1, sred);
    const float mh = hs / Hdim;
    const float rh = rsqrtf(hq / Hdim - mh * mh + 1e-5f);
#pragma unroll
    for (int tI = 0; tI < 3; tI++) {
        const int j = threadIdx.x + tI * 256;
        hout[(long)m * Hdim + j] = __float2bfloat16((hv[tI] - mh) * rh * gh[j] + bh[j]);
    }
}

// ---------------- launch ----------------
extern "C" void kernel_launch(void* const* d_in, const int* in_sizes, int n_in,
                              void* d_out, int out_size, void* d_ws, size_t ws_size,
                              hipStream_t stream) {
    (void)in_sizes; (void)n_in; (void)out_size; (void)ws_size;
    const float* x      = (const float*)d_in[0];
    const float* Wioux  = (const float*)d_in[1];
    const float* b_ioux = (const float*)d_in[2];
    const float* Wiouh  = (const float*)d_in[3];
    const float* Wfx    = (const float*)d_in[4];
    const float* b_fx   = (const float*)d_in[5];
    const float* Wfh    = (const float*)d_in[6];
    const float* b_fh   = (const float*)d_in[7];
    const float* ln_c_g = (const float*)d_in[8];
    const float* ln_c_b = (const float*)d_in[9];
    const float* ln_h_g = (const float*)d_in[10];
    const float* ln_h_b = (const float*)d_in[11];
    const float* Wout   = (const float*)d_in[12];
    const float* b_out  = (const float*)d_in[13];
    float* out = (float*)d_out;

    // ---- workspace (~212 MB) ----
    char* p = (char*)d_ws;
    bf16* W_cat   = (bf16*)p; p += 8L * 3072 * 1536 * 2;   // 75.5 MB
    bf16* Wfh_bf  = (bf16*)p; p += 8L * 768 * 768 * 2;     //  9.4 MB
    bf16* Wout_bf = (bf16*)p; p += 768L * 768 * 2;         //  1.2 MB
    float* b_cat  = (float*)p; p += 8L * 3072 * 4;         //  0.1 MB
    bf16* leafA   = (bf16*)p; p += 16384L * 768 * 2;       // 25.2 MB (fhb overlay)
    bf16* A6      = (bf16*)p; p += 8192L * 1536 * 2;       // 25.2 MB
    bf16* A5      = (bf16*)p; p += 4096L * 1536 * 2;       // 12.6 MB
    bf16* Cbuf    = (bf16*)p; p += 4096L * 3072 * 2;       // 25.2 MB
    bf16* hA      = (bf16*)p; p += 16384L * 768 * 2;       // 25.2 MB
    bf16* hB      = (bf16*)p; p += 8192L * 768 * 2;        // 12.6 MB
    bf16* fhb     = leafA;  // leafA dead once leaf GEMMs complete
    bf16* Cleaf   = A5;     // A5+Cbuf contiguous = exactly 8192*2304*2 bytes

    // ---- prep (2 launches) ----
    conv_wcat<<<8 * 3072, 384, 0, stream>>>(Wioux, Wiouh, Wfx, W_cat);
    prep_misc<<<5280 + 16384, 256, 0, stream>>>(
        Wfh, Wout, b_ioux, b_fx, x, Wfh_bf, Wout_bf, b_cat, leafA);

    GemmDesc dummy = mkdesc(nullptr, 0, nullptr, 0, nullptr, nullptr, 0, 0, 0, 1,
                            nullptr, 0);

    // ---- leaf level l=7 (M=16384, 2 chunks of 8192; C overlays A5+Cbuf) ----
    for (int c = 0; c < 2; c++) {
        const int m0 = c * 8192;
        GemmDesc dl = mkdesc(leafA + (long)m0 * 768, 768,
                             W_cat + 7L * 3072 * 1536, 1536, b_cat + 7 * 3072,
                             Cleaf, 2304, 0, 768, 9, nullptr, 0);
        gemm8_dual<<<9 * 32, 512, 0, stream>>>(dl, 9 * 32, dummy);
        pointwise_pair<<<4096, 256, 0, stream>>>(
            Cleaf, 2304, nullptr, nullptr, x, nullptr,
            ln_c_g + 7 * Hdim, ln_c_b + 7 * Hdim, ln_h_g + 7 * Hdim, ln_h_b + 7 * Hdim,
            hA + (long)m0 * Hdim, A6, m0, 6);
    }

    // ---- levels 6..1: dual 256^2 GEMM (iou + fh) then pointwise ----
    const int CH = 4096;
    bf16* hp = hA; bf16* hc = hB;
    bf16* Acur = A6; bf16* Anxt = A5;
    for (int l = 6; l >= 1; l--) {
        const int M = 128 << l;
        const int Mc = (M < CH) ? M : CH;
        const int nch = M / Mc;
        for (int c = 0; c < nch; c++) {
            const int m0 = c * Mc;
            GemmDesc diou = mkdesc(Acur + (long)m0 * 1536, 1536,
                                   W_cat + (long)l * 3072 * 1536, 1536,
                                   b_cat + l * 3072, Cbuf, 3072, 0, 1536, 12,
                                   nullptr, 0);
            GemmDesc dfh = mkdesc(hp + (long)2 * m0 * Hdim, 768,
                                  Wfh_bf + (long)l * 768 * 768, 768, nullptr,
                                  fhb, 768, 0, 768, 3, nullptr, 0);
            const int na = 12 * (Mc / 256);
            const int nb = 3 * (2 * Mc / 256);
            gemm8_dual<<<na + nb, 512, 0, stream>>>(diou, na, dfh);
            pointwise_pair<<<Mc / 2, 256, 0, stream>>>(
                Cbuf, 3072, fhb, hp + (long)2 * m0 * Hdim, x, b_fh + l * Hdim,
                ln_c_g + l * Hdim, ln_c_b + l * Hdim, ln_h_g + l * Hdim, ln_h_b + l * Hdim,
                hc + (long)m0 * Hdim, Anxt, m0, l - 1);
        }
        bf16* t1 = hp; hp = hc; hc = t1;
        bf16* t2 = Acur; Acur = Anxt; Anxt = t2;
    }

    // ---- root level l=0 (M=128, old 128^2 kernel) ----
    {
        GemmDesc diou = mkdesc(Acur, 1536, W_cat, 1536, b_cat, Cbuf, 3072, 0,
                               1536, 24, nullptr, 0);
        GemmDesc dfh = mkdesc(hp, 768, Wfh_bf, 768, nullptr, fhb, 768, 0,
                              768, 6, nullptr, 0);
        gemm_dual<<<24 + 12, 256, 0, stream>>>(diou, 24, dfh);
        pointwise_root<<<128, 256, 0, stream>>>(
            Cbuf, 3072, fhb, hp, b_fh,
            ln_c_g, ln_c_b, ln_h_g, ln_h_b, hc);
    }

    // ---- out = h_root @ Wout^T + b_out + x[:,0] ----
    {
        GemmDesc dout = mkdesc(hc, 768, Wout_bf, 768, b_out, out, 768, 1,
                               768, 6, x, 255L * 768);
        gemm_dual<<<6, 256, 0, stream>>>(dout, 6, dummy);
    }
}

// Round 2
// 1003.365 us; speedup vs baseline: 1.0572x; 1.0371x over previous
//
#include <hip/hip_runtime.h>
#include <hip/hip_bf16.h>

// TreeLSTM (child-sum, complete binary tree, DEPTH=8) on MI355X.
// Round 6: (a) fixed LDS swizzle in gemm8 — old (row&4) XOR left row out of
// the bank index => 8-way conflicts/ds_read_b128; new (row&7)<<4 XOR spreads
// to 2-way (T2, pays only in 8-phase regime). (b) level-6 packing: full-level
// fh GEMM rides in chunk0's dispatch (iou-first id order so short fh blocks
// fill the scheduler tail); chunk1 dispatch is iou-only.

#define Hdim 768

typedef __hip_bfloat16 bf16;
typedef __attribute__((ext_vector_type(8))) short short8;
typedef __attribute__((ext_vector_type(4))) float floatx4;

__device__ inline float b2f(unsigned short u) {
    union { unsigned int i; float f; } v; v.i = ((unsigned int)u) << 16; return v.f;
}
__device__ inline float b2f(bf16 h) { return b2f(*(unsigned short*)&h); }
__device__ inline unsigned short f2bu(float f) {
    bf16 h = __float2bfloat16(f);
    return *(unsigned short*)&h;
}
__device__ inline ushort4 cvt4(float4 v) {
    ushort4 o; o.x = f2bu(v.x); o.y = f2bu(v.y); o.z = f2bu(v.z); o.w = f2bu(v.w);
    return o;
}

// ---------------- weight prep ----------------
// W_cat[l] : [3072][1536] = [[Wioux[l] | Wiouh[l]]; [Wfx[l] | 0]]
__global__ __launch_bounds__(384) void conv_wcat(
    const float* __restrict__ Wioux, const float* __restrict__ Wiouh,
    const float* __restrict__ Wfx, bf16* __restrict__ W_cat)
{
    const int row = blockIdx.x;          // 0 .. 8*3072-1
    const int l = row / 3072;
    const int g = row % 3072;
    const int t = threadIdx.x;
    const int k2 = t << 2;
    float4 v;
    if (g < 2304) {
        const float* src = (k2 < 768)
            ? Wioux + ((long)l * 2304 + g) * 768 + k2
            : Wiouh + ((long)l * 2304 + g) * 768 + (k2 - 768);
        v = *(const float4*)src;
    } else if (k2 < 768) {
        v = *(const float4*)(Wfx + ((long)l * 768 + (g - 2304)) * 768 + k2);
    } else {
        v = make_float4(0.f, 0.f, 0.f, 0.f);
    }
    ((ushort4*)(W_cat + (long)row * 1536))[t] = cvt4(v);
}

// Merged prep: Wfh f2b [0,4608) | Wout f2b [4608,5184) | b_cat [5184,5280)
//            | leaf conv [5280, 5280+16384)
__global__ __launch_bounds__(256) void prep_misc(
    const float* __restrict__ Wfh, const float* __restrict__ Wout,
    const float* __restrict__ b_ioux, const float* __restrict__ b_fx,
    const float* __restrict__ x,
    bf16* __restrict__ Wfh_bf, bf16* __restrict__ Wout_bf,
    float* __restrict__ b_cat, bf16* __restrict__ leafA)
{
    const int id = blockIdx.x;
    const int t = threadIdx.x;
    if (id < 4608) {
        const long i = (long)id * 256 + t;
        ((ushort4*)Wfh_bf)[i] = cvt4(((const float4*)Wfh)[i]);
    } else if (id < 5184) {
        const long i = (long)(id - 4608) * 256 + t;
        ((ushort4*)Wout_bf)[i] = cvt4(((const float4*)Wout)[i]);
    } else if (id < 5280) {
        const int i = (id - 5184) * 256 + t;   // 0..24575
        const int l = i / 3072, g = i % 3072;
        b_cat[i] = (g < 2304) ? b_ioux[l * 2304 + g] : b_fx[l * 768 + (g - 2304)];
    } else if (t < 192) {
        const int m = id - 5280;               // 0..16383
        const int b = m >> 7, j = m & 127;
        const float* xr = x + ((long)b * 255 + 127 + j) * Hdim;
        ((ushort4*)(leafA + (long)m * Hdim))[t] = cvt4(((const float4*)xr)[t]);
    }
}

// ---------------- GEMM descriptors ----------------
struct GemmDesc {
    const bf16* A; int lda;
    const bf16* W; int ldw;
    const float* bias;
    void* C; int ldc; int c_fp32;
    int K; int nxb;                      // n-blocks (N / tile_n of the kernel used)
    const float* addv; long add_stride;
};

static inline GemmDesc mkdesc(const bf16* A, int lda, const bf16* W, int ldw,
                              const float* bias, void* C, int ldc, int c_fp32,
                              int K, int nxb, const float* addv, long add_stride) {
    GemmDesc d; d.A = A; d.lda = lda; d.W = W; d.ldw = ldw; d.bias = bias;
    d.C = C; d.ldc = ldc; d.c_fp32 = c_fp32; d.K = K; d.nxb = nxb;
    d.addv = addv; d.add_stride = add_stride; return d;
}

// ---------------- small MFMA GEMM (root/out only; 128x128, nxb = N/128) ----
__global__ __launch_bounds__(256) void gemm_dual(GemmDesc da, int na, GemmDesc db)
{
    __shared__ __align__(16) bf16 As[128 * 32];
    __shared__ __align__(16) bf16 Ws[128 * 32];
    int id = blockIdx.x;
    const bool second = (id >= na);
    if (second) id -= na;
    const GemmDesc d = second ? db : da;
    const int bm = id / d.nxb, bn = id % d.nxb;

    const int t = threadIdx.x;
    const int wave = t >> 6, lane = t & 63;
    const long m_blk = (long)bm << 7;
    const long n_blk = (long)bn << 7;

    const int srow = (wave << 5) + (lane >> 2);
    const int sbyte = (lane & 3) << 4;
    const char* gA = (const char*)(d.A + (m_blk + srow) * (long)d.lda) + sbyte;
    const char* gW = (const char*)(d.W + (n_blk + srow) * (long)d.ldw) + sbyte;
    const long aRow16 = (long)d.lda * 32;
    const long wRow16 = (long)d.ldw * 32;
    bf16* lA = As + (wave << 10);
    bf16* lW = Ws + (wave << 10);

    floatx4 zero = {0.f, 0.f, 0.f, 0.f};
    floatx4 acc[4][4];
#pragma unroll
    for (int i = 0; i < 4; i++)
#pragma unroll
        for (int j = 0; j < 4; j++) acc[i][j] = zero;

    const int mrow = (wave & 1) << 6;
    const int ncol = (wave >> 1) << 6;
    const short* AsS = (const short*)As;
    const short* WsS = (const short*)Ws;
    const int fm = lane & 15;
    const int fk = (lane >> 4) << 3;

    for (int k0 = 0; k0 < d.K; k0 += 32) {
        __builtin_amdgcn_global_load_lds(
            (const __attribute__((address_space(1))) unsigned int*)gA,
            (__attribute__((address_space(3))) unsigned int*)lA, 16, 0, 0);
        __builtin_amdgcn_global_load_lds(
            (const __attribute__((address_space(1))) unsigned int*)(gA + aRow16),
            (__attribute__((address_space(3))) unsigned int*)(lA + 512), 16, 0, 0);
        __builtin_amdgcn_global_load_lds(
            (const __attribute__((address_space(1))) unsigned int*)gW,
            (__attribute__((address_space(3))) unsigned int*)lW, 16, 0, 0);
        __builtin_amdgcn_global_load_lds(
            (const __attribute__((address_space(1))) unsigned int*)(gW + wRow16),
            (__attribute__((address_space(3))) unsigned int*)(lW + 512), 16, 0, 0);
        gA += 64; gW += 64;
        __syncthreads();

        short8 af[4], bfr[4];
#pragma unroll
        for (int i = 0; i < 4; i++) {
            af[i]  = *(const short8*)(AsS + (mrow + i * 16 + fm) * 32 + fk);
            bfr[i] = *(const short8*)(WsS + (ncol + i * 16 + fm) * 32 + fk);
        }
#pragma unroll
        for (int i = 0; i < 4; i++)
#pragma unroll
            for (int j = 0; j < 4; j++)
                acc[i][j] = __builtin_amdgcn_mfma_f32_16x16x32_bf16(
                    af[i], bfr[j], acc[i][j], 0, 0, 0);
        __syncthreads();
    }

    const int crow0 = (lane >> 4) << 2;
    const int ccol = lane & 15;
#pragma unroll
    for (int i = 0; i < 4; i++) {
#pragma unroll
        for (int j = 0; j < 4; j++) {
            const long col = n_blk + ncol + j * 16 + ccol;
            const float bv = d.bias ? d.bias[col] : 0.f;
#pragma unroll
            for (int r = 0; r < 4; r++) {
                const long row = m_blk + mrow + i * 16 + crow0 + r;
                float v = acc[i][j][r] + bv;
                if (d.addv) v += d.addv[row * d.add_stride + col];
                if (d.c_fp32) ((float*)d.C)[row * (long)d.ldc + col] = v;
                else ((bf16*)d.C)[row * (long)d.ldc + col] = __float2bfloat16(v);
            }
        }
    }
}

// ---------------- big MFMA GEMM: 256x256 tile, BK=64, 8 waves, 8-phase ----
// nxb = N/256; M multiple of 256, K multiple of 64 (>=128).
// LDS swizzle: content stored as LDS[r][cb] = G[r][cb ^ ((r&7)<<4)].
// Write side (global_load_lds dest is linear lane*16): pre-swizzle the global
// SOURCE column: colb = ((lane&7) ^ ((lane>>3)&7)) << 4  (r&7 == (lane>>3)&7).
// Read side: row&7 == lane&7 (row bases are multiples of 16 + (lane&15)), so
// col' = (ks*64 + fkB) ^ ((lane&7)<<4), precomputed as cx0 / cx1 = cx0^64.
// Bank spread per 16-lane phase: 8 distinct bank-quads, 2 rows each (2-way =
// free) vs previous 8-way.
__global__ __launch_bounds__(512, 2) void gemm8_dual(GemmDesc da, int na, GemmDesc db)
{
    __shared__ __align__(16) char smem[131072];   // A: [2][32K] @0, B @65536

    int id = blockIdx.x;
    int nwg = na;
    bool second = false;
    if (id >= na) { id -= na; nwg = (int)gridDim.x - na; second = true; }
    const GemmDesc d = second ? db : da;
    {   // bijective XCD swizzle (8 XCDs), m204 variant
        const int q = nwg >> 3, r = nwg & 7;
        const int x = id & 7, i2 = id >> 3;
        id = (x < r ? x * (q + 1) : r * (q + 1) + (x - r) * q) + i2;
    }
    const int bm = id / d.nxb, bn = id % d.nxb;
    const int tid = threadIdx.x;
    const int w = tid >> 6, lane = tid & 63;
    const long m_blk = (long)bm << 8;
    const long n_blk = (long)bn << 8;
    const int T = d.K >> 6;                       // K-tiles (>=2 for all users)

    // ---- staging addressing (pre-swizzled source, linear LDS dest)
    const int colb = (((lane & 7) ^ ((lane >> 3) & 7)) << 4);
    const int rw = (w << 4) + (lane >> 3);
    const long ldaB = (long)d.lda * 2, ldwB = (long)d.ldw * 2;
    const char* gA0 = (const char*)(d.A + m_blk * d.lda) + (long)rw * ldaB + colb;
    const char* gB0 = (const char*)(d.W + n_blk * d.ldw) + (long)rw * ldwB + colb;
    const long aH = ldaB << 7, bH = ldwB << 7;    // +128 rows (half 1)
    const long a8 = ldaB << 3, b8 = ldwB << 3;    // +8 rows (second instr)
    char* lW = smem + (w << 11);

    auto stageA = [&](int tile, int buf, int half) {
        const char* g = gA0 + (half ? aH : 0) + ((long)tile << 7);
        char* l = lW + buf * 32768 + half * 16384;
        __builtin_amdgcn_global_load_lds(
            (const __attribute__((address_space(1))) unsigned int*)g,
            (__attribute__((address_space(3))) unsigned int*)l, 16, 0, 0);
        __builtin_amdgcn_global_load_lds(
            (const __attribute__((address_space(1))) unsigned int*)(g + a8),
            (__attribute__((address_space(3))) unsigned int*)(l + 1024), 16, 0, 0);
    };
    auto stageB = [&](int tile, int buf, int half) {
        const char* g = gB0 + (half ? bH : 0) + ((long)tile << 7);
        char* l = lW + 65536 + buf * 32768 + half * 16384;
        __builtin_amdgcn_global_load_lds(
            (const __attribute__((address_space(1))) unsigned int*)g,
            (__attribute__((address_space(3))) unsigned int*)l, 16, 0, 0);
        __builtin_amdgcn_global_load_lds(
            (const __attribute__((address_space(1))) unsigned int*)(g + b8),
            (__attribute__((address_space(3))) unsigned int*)(l + 1024), 16, 0, 0);
    };

    // ---- fragment read addressing
    const int fm = lane & 15;
    const int fkB = (lane >> 4) << 4;
    const int sx = (lane & 7) << 4;
    const int cx0 = fkB ^ sx;
    const int cx1 = cx0 ^ 64;
    const int arow0 = ((w >> 2) << 7) + fm;       // wr*128 + fm
    const int brow0 = ((w & 3) << 6) + fm;        // wc*64 + fm

    floatx4 acc[8][4];
    const floatx4 fzero = {0.f, 0.f, 0.f, 0.f};
#pragma unroll
    for (int i = 0; i < 8; i++)
#pragma unroll
        for (int j = 0; j < 4; j++) acc[i][j] = fzero;

    // ---- prologue ----
    stageA(0, 0, 0); stageA(0, 0, 1); stageB(0, 0, 0); stageB(0, 0, 1);
    if (T > 1) {
        stageB(1, 1, 0); stageB(1, 1, 1); stageA(1, 1, 0);
        asm volatile("s_waitcnt vmcnt(6)" ::: "memory");
    } else {
        asm volatile("s_waitcnt vmcnt(0)" ::: "memory");
    }
    __builtin_amdgcn_sched_barrier(0);
    __builtin_amdgcn_s_barrier();
    __builtin_amdgcn_sched_barrier(0);

    short8 a[4][2], b[4][2];
    for (int tt = 0; tt < T; ++tt) {
        const int buf = tt & 1;
        const char* la = smem + buf * 32768;
        const char* lb = smem + 65536 + buf * 32768;
        // ---------- P1
#pragma unroll
        for (int mf = 0; mf < 4; ++mf) {
            a[mf][0] = *(const short8*)(la + ((arow0 + mf * 16) << 7) + cx0);
            a[mf][1] = *(const short8*)(la + ((arow0 + mf * 16) << 7) + cx1);
        }
#pragma unroll
        for (int nf = 0; nf < 2; ++nf) {
            b[nf][0] = *(const short8*)(lb + ((brow0 + nf * 16) << 7) + cx0);
            b[nf][1] = *(const short8*)(lb + ((brow0 + nf * 16) << 7) + cx1);
        }
        if (tt + 1 < T) stageA(tt + 1, buf ^ 1, 1);
        __builtin_amdgcn_s_barrier();
        asm volatile("s_waitcnt lgkmcnt(0)" ::: "memory");
        __builtin_amdgcn_sched_barrier(0);
        __builtin_amdgcn_s_setprio(1);
#pragma unroll
        for (int ks = 0; ks < 2; ++ks)
#pragma unroll
            for (int mf = 0; mf < 4; ++mf)
#pragma unroll
                for (int nf = 0; nf < 2; ++nf)
                    acc[mf][nf] = __builtin_amdgcn_mfma_f32_16x16x32_bf16(
                        a[mf][ks], b[nf][ks], acc[mf][nf], 0, 0, 0);
        __builtin_amdgcn_s_setprio(0);
        __builtin_amdgcn_s_barrier();
        __builtin_amdgcn_sched_barrier(0);
        // ---------- P2
#pragma unroll
        for (int nf = 0; nf < 2; ++nf) {
            b[2 + nf][0] = *(const short8*)(lb + ((brow0 + (2 + nf) * 16) << 7) + cx0);
            b[2 + nf][1] = *(const short8*)(lb + ((brow0 + (2 + nf) * 16) << 7) + cx1);
        }
        __builtin_amdgcn_s_barrier();
        asm volatile("s_waitcnt lgkmcnt(0)" ::: "memory");
        __builtin_amdgcn_sched_barrier(0);
        __builtin_amdgcn_s_setprio(1);
#pragma unroll
        for (int ks = 0; ks < 2; ++ks)
#pragma unroll
            for (int mf = 0; mf < 4; ++mf)
#pragma unroll
                for (int nf = 0; nf < 2; ++nf)
                    acc[mf][2 + nf] = __builtin_amdgcn_mfma_f32_16x16x32_bf16(
                        a[mf][ks], b[2 + nf][ks], acc[mf][2 + nf], 0, 0, 0);
        __builtin_amdgcn_s_setprio(0);
        __builtin_amdgcn_s_barrier();
        __builtin_amdgcn_sched_barrier(0);
        // ---------- P3
#pragma unroll
        for (int mf = 0; mf < 4; ++mf) {
            a[mf][0] = *(const short8*)(la + ((arow0 + (4 + mf) * 16) << 7) + cx0);
            a[mf][1] = *(const short8*)(la + ((arow0 + (4 + mf) * 16) << 7) + cx1);
        }
        if (tt + 2 < T) stageB(tt + 2, buf, 0);
        __builtin_amdgcn_s_barrier();
        asm volatile("s_waitcnt lgkmcnt(0)" ::: "memory");
        __builtin_amdgcn_sched_barrier(0);
        __builtin_amdgcn_s_setprio(1);
#pragma unroll
        for (int ks = 0; ks < 2; ++ks)
#pragma unroll
            for (int mf = 0; mf < 4; ++mf)
#pragma unroll
                for (int nf = 0; nf < 2; ++nf)
                    acc[4 + mf][2 + nf] = __builtin_amdgcn_mfma_f32_16x16x32_bf16(
                        a[mf][ks], b[2 + nf][ks], acc[4 + mf][2 + nf], 0, 0, 0);
        __builtin_amdgcn_s_setprio(0);
        __builtin_amdgcn_s_barrier();
        __builtin_amdgcn_sched_barrier(0);
        // ---------- P4 (no ds reads; stages overlap MFMA)
        if (tt + 2 < T) { stageB(tt + 2, buf, 1); stageA(tt + 2, buf, 0); }
        __builtin_amdgcn_s_setprio(1);
#pragma unroll
        for (int ks = 0; ks < 2; ++ks)
#pragma unroll
            for (int mf = 0; mf < 4; ++mf)
#pragma unroll
                for (int nf = 0; nf < 2; ++nf)
                    acc[4 + mf][nf] = __builtin_amdgcn_mfma_f32_16x16x32_bf16(
                        a[mf][ks], b[nf][ks], acc[4 + mf][nf], 0, 0, 0);
        __builtin_amdgcn_s_setprio(0);
        if (tt + 1 < T) {
            if (tt + 2 < T) asm volatile("s_waitcnt vmcnt(6)" ::: "memory");
            else            asm volatile("s_waitcnt vmcnt(0)" ::: "memory");
            __builtin_amdgcn_sched_barrier(0);
            __builtin_amdgcn_s_barrier();
            __builtin_amdgcn_sched_barrier(0);
        }
    }

    // ---------- epilogue ----------
    const int crow = (lane >> 4) << 2;
    const int ccol = lane & 15;
    const long row0 = m_blk + ((long)(w >> 2) << 7);
    const long col0 = n_blk + ((w & 3) << 6);
#pragma unroll
    for (int mf = 0; mf < 8; ++mf) {
#pragma unroll
        for (int nf = 0; nf < 4; ++nf) {
            const long col = col0 + nf * 16 + ccol;
            const float bv = d.bias ? d.bias[col] : 0.f;
#pragma unroll
            for (int r = 0; r < 4; ++r) {
                const long row = row0 + mf * 16 + crow + r;
                const float v = acc[mf][nf][r] + bv;
                if (d.c_fp32) ((float*)d.C)[row * (long)d.ldc + col] = v;
                else ((bf16*)d.C)[row * (long)d.ldc + col] = __float2bfloat16(v);
            }
        }
    }
}

// ---------------- pointwise ----------------
__device__ inline float sigf(float x) { return 1.f / (1.f + __expf(-x)); }
__device__ inline float tanh_fast(float x) { return 2.f / (1.f + __expf(-2.f * x)) - 1.f; }

__device__ inline void block_reduce4(float& a, float& b, float& c, float& d,
                                     float* s) {
#pragma unroll
    for (int off = 32; off > 0; off >>= 1) {
        a += __shfl_down(a, off, 64);
        b += __shfl_down(b, off, 64);
        c += __shfl_down(c, off, 64);
        d += __shfl_down(d, off, 64);
    }
    const int lane = threadIdx.x & 63, w = threadIdx.x >> 6;
    __syncthreads();
    if (lane == 0) { s[w] = a; s[w + 4] = b; s[w + 8] = c; s[w + 12] = d; }
    __syncthreads();
    a = s[0] + s[1] + s[2] + s[3];
    b = s[4] + s[5] + s[6] + s[7];
    c = s[8] + s[9] + s[10] + s[11];
    d = s[12] + s[13] + s[14] + s[15];
}

// Block handles sibling rows 2p,2p+1 (chunk-local). Writes h rows and the
// next level's A_cat row [xs | h0+h1] at parent index.
__global__ __launch_bounds__(256) void pointwise_pair(
    const bf16* __restrict__ C, int ldc,
    const bf16* __restrict__ fhb,
    const bf16* __restrict__ hprev2,
    const float* __restrict__ x,
    const float* __restrict__ bfh,
    const float* __restrict__ gc, const float* __restrict__ bc,
    const float* __restrict__ gh, const float* __restrict__ bh,
    bf16* __restrict__ hout,
    bf16* __restrict__ Anext,
    int m0, int lp)
{
    __shared__ float sred[16];
    const int pl = blockIdx.x;
    const bf16* cr0 = C + (long)(2 * pl) * ldc;
    const bf16* cr1 = cr0 + ldc;
    float c0v[3], c1v[3], o0v[3], o1v[3], h0v[3], h1v[3];
    float s0 = 0.f, q0 = 0.f, s1 = 0.f, q1 = 0.f;
#pragma unroll
    for (int tI = 0; tI < 3; tI++) {
        const int j = threadIdx.x + tI * 256;
        const float i0 = sigf(b2f(cr0[j]));
        const float i1 = sigf(b2f(cr1[j]));
        o0v[tI] = b2f(cr0[Hdim + j]);
        o1v[tI] = b2f(cr1[Hdim + j]);
        float c0 = i0 * tanh_fast(b2f(cr0[2 * Hdim + j]));
        float c1 = i1 * tanh_fast(b2f(cr1[2 * Hdim + j]));
        if (fhb) {
            const float bfhj = bfh[j];
            const float fx0 = b2f(cr0[3 * Hdim + j]);
            const float fx1 = b2f(cr1[3 * Hdim + j]);
            const long base = (long)(4 * pl) * Hdim + j;
            const float f00 = sigf(fx0 + b2f(fhb[base]) + bfhj);
            const float f01 = sigf(fx0 + b2f(fhb[base + Hdim]) + bfhj);
            const float f10 = sigf(fx1 + b2f(fhb[base + 2 * Hdim]) + bfhj);
            const float f11 = sigf(fx1 + b2f(fhb[base + 3 * Hdim]) + bfhj);
            c0 += f00 * b2f(hprev2[base]) + f01 * b2f(hprev2[base + Hdim]);
            c1 += f10 * b2f(hprev2[base + 2 * Hdim]) + f11 * b2f(hprev2[base + 3 * Hdim]);
        }
        c0v[tI] = c0; c1v[tI] = c1;
        s0 += c0; q0 += c0 * c0; s1 += c1; q1 += c1 * c1;
    }
    block_reduce4(s0, q0, s1, q1, sred);
    const float m0c = s0 / Hdim, m1c = s1 / Hdim;
    const float r0c = rsqrtf(q0 / Hdim - m0c * m0c + 1e-5f);
    const float r1c = rsqrtf(q1 / Hdim - m1c * m1c + 1e-5f);
    float hs0 = 0.f, hq0 = 0.f, hs1 = 0.f, hq1 = 0.f;
#pragma unroll
    for (int tI = 0; tI < 3; tI++) {
        const int j = threadIdx.x + tI * 256;
        const float cn0 = (c0v[tI] - m0c) * r0c * gc[j] + bc[j];
        const float cn1 = (c1v[tI] - m1c) * r1c * gc[j] + bc[j];
        const float h0 = sigf(o0v[tI]) * tanh_fast(cn0);
        const float h1 = sigf(o1v[tI]) * tanh_fast(cn1);
        h0v[tI] = h0; h1v[tI] = h1;
        hs0 += h0; hq0 += h0 * h0; hs1 += h1; hq1 += h1 * h1;
    }
    block_reduce4(hs0, hq0, hs1, hq1, sred);
    const float mh0 = hs0 / Hdim, mh1 = hs1 / Hdim;
    const float rh0 = rsqrtf(hq0 / Hdim - mh0 * mh0 + 1e-5f);
    const float rh1 = rsqrtf(hq1 / Hdim - mh1 * mh1 + 1e-5f);

    const int pg = m0 / 2 + pl;
    const int b = pg >> lp;
    const int jn = pg & ((1 << lp) - 1);
    const float* xr = x + ((long)b * 255 + (1 << lp) - 1 + jn) * Hdim;
    bf16* arow = Anext + (long)pg * 1536;
#pragma unroll
    for (int tI = 0; tI < 3; tI++) {
        const int j = threadIdx.x + tI * 256;
        const float h0 = (h0v[tI] - mh0) * rh0 * gh[j] + bh[j];
        const float h1 = (h1v[tI] - mh1) * rh1 * gh[j] + bh[j];
        hout[(long)(2 * pl) * Hdim + j] = __float2bfloat16(h0);
        hout[(long)(2 * pl + 1) * Hdim + j] = __float2bfloat16(h1);
        arow[768 + j] = __float2bfloat16(h0 + h1);
        arow[j] = __float2bfloat16(xr[j]);
    }
}

__global__ __launch_bounds__(256) void pointwise_root(
    const bf16* __restrict__ C, int ldc,
    const bf16* __restrict__ fhb, const bf16* __restrict__ hprev,
    const float* __restrict__ bfh,
    const float* __restrict__ gc, const float* __restrict__ bc,
    const float* __restrict__ gh, const float* __restrict__ bh,
    bf16* __restrict__ hout)
{
    __shared__ float sred[16];
    const int m = blockIdx.x;
    const bf16* cr = C + (long)m * ldc;
    float cv[3], ov[3], hv[3];
    float ssum = 0.f, ssq = 0.f, d0 = 0.f, d1 = 0.f;
#pragma unroll
    for (int tI = 0; tI < 3; tI++) {
        const int j = threadIdx.x + tI * 256;
        const float i_ = sigf(b2f(cr[j]));
        ov[tI] = b2f(cr[Hdim + j]);
        float c = i_ * tanh_fast(b2f(cr[2 * Hdim + j]));
        const float fx = b2f(cr[3 * Hdim + j]);
        const float bfhj = bfh[j];
        const long base = (long)(2 * m) * Hdim + j;
        const float f0 = sigf(fx + b2f(fhb[base]) + bfhj);
        const float f1 = sigf(fx + b2f(fhb[base + Hdim]) + bfhj);
        c += f0 * b2f(hprev[base]) + f1 * b2f(hprev[base + Hdim]);
        cv[tI] = c; ssum += c; ssq += c * c;
    }
    block_reduce4(ssum, ssq, d0, d1, sred);
    const float mean = ssum / Hdim;
    const float rstd = rsqrtf(ssq / Hdim - mean * mean + 1e-5f);
    float hs = 0.f, hq = 0.f;
#pragma unroll
    for (int tI = 0; tI < 3; tI++) {
        const int j = threadIdx.x + tI * 256;
        const float cn = (cv[tI] - mean) * rstd * gc[j] + bc[j];
        const float h = sigf(ov[tI]) * tanh_fast(cn);
        hv[tI] = h; hs += h; hq += h * h;
    }
    d0 = 0.f; d1 = 0.f;
    block_reduce4(hs, hq, d0, d1, sred);
    const float mh = hs / Hdim;
    const float rh = rsqrtf(hq / Hdim - mh * mh + 1e-5f);
#pragma unroll
    for (int tI = 0; tI < 3; tI++) {
        const int j = threadIdx.x + tI * 256;
        hout[(long)m * Hdim + j] = __float2bfloat16((hv[tI] - mh) * rh * gh[j] + bh[j]);
    }
}

// ---------------- launch ----------------
extern "C" void kernel_launch(void* const* d_in, const int* in_sizes, int n_in,
                              void* d_out, int out_size, void* d_ws, size_t ws_size,
                              hipStream_t stream) {
    (void)in_sizes; (void)n_in; (void)out_size; (void)ws_size;
    const float* x      = (const float*)d_in[0];
    const float* Wioux  = (const float*)d_in[1];
    const float* b_ioux = (const float*)d_in[2];
    const float* Wiouh  = (const float*)d_in[3];
    const float* Wfx    = (const float*)d_in[4];
    const float* b_fx   = (const float*)d_in[5];
    const float* Wfh    = (const float*)d_in[6];
    const float* b_fh   = (const float*)d_in[7];
    const float* ln_c_g = (const float*)d_in[8];
    const float* ln_c_b = (const float*)d_in[9];
    const float* ln_h_g = (const float*)d_in[10];
    const float* ln_h_b = (const float*)d_in[11];
    const float* Wout   = (const float*)d_in[12];
    const float* b_out  = (const float*)d_in[13];
    float* out = (float*)d_out;

    // ---- workspace (~212 MB) ----
    char* p = (char*)d_ws;
    bf16* W_cat   = (bf16*)p; p += 8L * 3072 * 1536 * 2;   // 75.5 MB
    bf16* Wfh_bf  = (bf16*)p; p += 8L * 768 * 768 * 2;     //  9.4 MB
    bf16* Wout_bf = (bf16*)p; p += 768L * 768 * 2;         //  1.2 MB
    float* b_cat  = (float*)p; p += 8L * 3072 * 4;         //  0.1 MB
    bf16* leafA   = (bf16*)p; p += 16384L * 768 * 2;       // 25.2 MB (fhb overlay)
    bf16* A6      = (bf16*)p; p += 8192L * 1536 * 2;       // 25.2 MB
    bf16* A5      = (bf16*)p; p += 4096L * 1536 * 2;       // 12.6 MB
    bf16* Cbuf    = (bf16*)p; p += 4096L * 3072 * 2;       // 25.2 MB
    bf16* hA      = (bf16*)p; p += 16384L * 768 * 2;       // 25.2 MB
    bf16* hB      = (bf16*)p; p += 8192L * 768 * 2;        // 12.6 MB
    bf16* fhb     = leafA;  // leafA dead once leaf GEMMs complete
    bf16* Cleaf   = A5;     // A5+Cbuf contiguous = exactly 8192*2304*2 bytes

    // ---- prep (2 launches) ----
    conv_wcat<<<8 * 3072, 384, 0, stream>>>(Wioux, Wiouh, Wfx, W_cat);
    prep_misc<<<5280 + 16384, 256, 0, stream>>>(
        Wfh, Wout, b_ioux, b_fx, x, Wfh_bf, Wout_bf, b_cat, leafA);

    GemmDesc dummy = mkdesc(nullptr, 0, nullptr, 0, nullptr, nullptr, 0, 0, 0, 1,
                            nullptr, 0);

    // ---- leaf level l=7 (M=16384, 2 chunks of 8192; C overlays A5+Cbuf) ----
    for (int c = 0; c < 2; c++) {
        const int m0 = c * 8192;
        GemmDesc dl = mkdesc(leafA + (long)m0 * 768, 768,
                             W_cat + 7L * 3072 * 1536, 1536, b_cat + 7 * 3072,
                             Cleaf, 2304, 0, 768, 9, nullptr, 0);
        gemm8_dual<<<9 * 32, 512, 0, stream>>>(dl, 9 * 32, dummy);
        pointwise_pair<<<4096, 256, 0, stream>>>(
            Cleaf, 2304, nullptr, nullptr, x, nullptr,
            ln_c_g + 7 * Hdim, ln_c_b + 7 * Hdim, ln_h_g + 7 * Hdim, ln_h_b + 7 * Hdim,
            hA + (long)m0 * Hdim, A6, m0, 6);
    }

    // ---- levels 6..1: 256^2 GEMMs; full-level fh rides in chunk0 dispatch ----
    const int CH = 4096;
    bf16* hp = hA; bf16* hc = hB;
    bf16* Acur = A6; bf16* Anxt = A5;
    for (int l = 6; l >= 1; l--) {
        const int M = 128 << l;
        const int Mc = (M < CH) ? M : CH;
        const int nch = M / Mc;
        for (int c = 0; c < nch; c++) {
            const int m0 = c * Mc;
            GemmDesc diou = mkdesc(Acur + (long)m0 * 1536, 1536,
                                   W_cat + (long)l * 3072 * 1536, 1536,
                                   b_cat + l * 3072, Cbuf, 3072, 0, 1536, 12,
                                   nullptr, 0);
            const int na = 12 * (Mc / 256);
            if (c == 0) {
                // fh for the WHOLE level (2M rows) in this dispatch; iou ids
                // first so the short fh blocks fill the scheduler tail.
                GemmDesc dfh = mkdesc(hp, 768,
                                      Wfh_bf + (long)l * 768 * 768, 768, nullptr,
                                      fhb, 768, 0, 768, 3, nullptr, 0);
                const int nb = 3 * (2 * M / 256);
                gemm8_dual<<<na + nb, 512, 0, stream>>>(diou, na, dfh);
            } else {
                gemm8_dual<<<na, 512, 0, stream>>>(diou, na, dummy);
            }
            pointwise_pair<<<Mc / 2, 256, 0, stream>>>(
                Cbuf, 3072, fhb + (long)2 * m0 * Hdim, hp + (long)2 * m0 * Hdim,
                x, b_fh + l * Hdim,
                ln_c_g + l * Hdim, ln_c_b + l * Hdim, ln_h_g + l * Hdim, ln_h_b + l * Hdim,
                hc + (long)m0 * Hdim, Anxt, m0, l - 1);
        }
        bf16* t1 = hp; hp = hc; hc = t1;
        bf16* t2 = Acur; Acur = Anxt; Anxt = t2;
    }

    // ---- root level l=0 (M=128, old 128^2 kernel) ----
    {
        GemmDesc diou = mkdesc(Acur, 1536, W_cat, 1536, b_cat, Cbuf, 3072, 0,
                               1536, 24, nullptr, 0);
        GemmDesc dfh = mkdesc(hp, 768, Wfh_bf, 768, nullptr, fhb, 768, 0,
                              768, 6, nullptr, 0);
        gemm_dual<<<24 + 12, 256, 0, stream>>>(diou, 24, dfh);
        pointwise_root<<<128, 256, 0, stream>>>(
            Cbuf, 3072, fhb, hp, b_fh,
            ln_c_g, ln_c_b, ln_h_g, ln_h_b, hc);
    }

    // ---- out = h_root @ Wout^T + b_out + x[:,0] ----
    {
        GemmDesc dout = mkdesc(hc, 768, Wout_bf, 768, b_out, out, 768, 1,
                               768, 6, x, 255L * 768);
        gemm_dual<<<6, 256, 0, stream>>>(dout, 6, dummy);
    }
}

// Round 3
// 989.994 us; speedup vs baseline: 1.0715x; 1.0135x over previous
//
#include <hip/hip_runtime.h>
#include <hip/hip_bf16.h>

// TreeLSTM (child-sum, complete binary tree, DEPTH=8) on MI355X.
// Round 7: grid-quantization attack. (a) gemm8 is now a persistent job-queue
// kernel (grid<=256, atomicAdd counter zeroed per-replay in prep_misc, long
// iou jobs first = LPT). (b) l6 reverted to per-chunk fh so both l6 dispatches
// carry the l5-like 192L+96S mix (makespan ~= 1 long block). (c) leaf split
// into 3 chunks of <=256 jobs (makespan ~= 1 block each). (d) levels 4..1 use
// the 128^2 gemm_dual (many small blocks, ~6/CU co-resident) instead of huge
// T=24 256^2 blocks. (e) pointwise vectorized: 192 lanes x ushort4/float4.

#define Hdim 768

typedef __hip_bfloat16 bf16;
typedef __attribute__((ext_vector_type(8))) short short8;
typedef __attribute__((ext_vector_type(4))) float floatx4;

__device__ inline float b2f(unsigned short u) {
    union { unsigned int i; float f; } v; v.i = ((unsigned int)u) << 16; return v.f;
}
__device__ inline float b2f(bf16 h) { return b2f(*(unsigned short*)&h); }
__device__ inline unsigned short f2bu(float f) {
    bf16 h = __float2bfloat16(f);
    return *(unsigned short*)&h;
}
__device__ inline ushort4 cvt4(float4 v) {
    ushort4 o; o.x = f2bu(v.x); o.y = f2bu(v.y); o.z = f2bu(v.z); o.w = f2bu(v.w);
    return o;
}
__device__ inline void ld4(const bf16* p, float* o) {
    ushort4 u = *(const ushort4*)p;
    o[0] = b2f(u.x); o[1] = b2f(u.y); o[2] = b2f(u.z); o[3] = b2f(u.w);
}
__device__ inline void st4(bf16* p, const float* v) {
    ushort4 u; u.x = f2bu(v[0]); u.y = f2bu(v[1]); u.z = f2bu(v[2]); u.w = f2bu(v[3]);
    *(ushort4*)p = u;
}

// ---------------- weight prep ----------------
// W_cat[l] : [3072][1536] = [[Wioux[l] | Wiouh[l]]; [Wfx[l] | 0]]
__global__ __launch_bounds__(384) void conv_wcat(
    const float* __restrict__ Wioux, const float* __restrict__ Wiouh,
    const float* __restrict__ Wfx, bf16* __restrict__ W_cat)
{
    const int row = blockIdx.x;          // 0 .. 8*3072-1
    const int l = row / 3072;
    const int g = row % 3072;
    const int t = threadIdx.x;
    const int k2 = t << 2;
    float4 v;
    if (g < 2304) {
        const float* src = (k2 < 768)
            ? Wioux + ((long)l * 2304 + g) * 768 + k2
            : Wiouh + ((long)l * 2304 + g) * 768 + (k2 - 768);
        v = *(const float4*)src;
    } else if (k2 < 768) {
        v = *(const float4*)(Wfx + ((long)l * 768 + (g - 2304)) * 768 + k2);
    } else {
        v = make_float4(0.f, 0.f, 0.f, 0.f);
    }
    ((ushort4*)(W_cat + (long)row * 1536))[t] = cvt4(v);
}

// Merged prep: Wfh f2b [0,4608) | Wout f2b [4608,5184) | b_cat [5184,5280)
//            | leaf conv [5280, 5280+16384) | job counters [21664]
__global__ __launch_bounds__(256) void prep_misc(
    const float* __restrict__ Wfh, const float* __restrict__ Wout,
    const float* __restrict__ b_ioux, const float* __restrict__ b_fx,
    const float* __restrict__ x,
    bf16* __restrict__ Wfh_bf, bf16* __restrict__ Wout_bf,
    float* __restrict__ b_cat, bf16* __restrict__ leafA,
    unsigned int* __restrict__ ctrs)
{
    const int id = blockIdx.x;
    const int t = threadIdx.x;
    if (id < 4608) {
        const long i = (long)id * 256 + t;
        ((ushort4*)Wfh_bf)[i] = cvt4(((const float4*)Wfh)[i]);
    } else if (id < 5184) {
        const long i = (long)(id - 4608) * 256 + t;
        ((ushort4*)Wout_bf)[i] = cvt4(((const float4*)Wout)[i]);
    } else if (id < 5280) {
        const int i = (id - 5184) * 256 + t;   // 0..24575
        const int l = i / 3072, g = i % 3072;
        b_cat[i] = (g < 2304) ? b_ioux[l * 2304 + g] : b_fx[l * 768 + (g - 2304)];
    } else if (id < 21664) {
        if (t < 192) {
            const int m = id - 5280;           // 0..16383
            const int b = m >> 7, j = m & 127;
            const float* xr = x + ((long)b * 255 + 127 + j) * Hdim;
            ((ushort4*)(leafA + (long)m * Hdim))[t] = cvt4(((const float4*)xr)[t]);
        }
    } else {
        if (t < 16) ctrs[t] = 0;               // persistent-GEMM job counters
    }
}

// ---------------- GEMM descriptors ----------------
struct GemmDesc {
    const bf16* A; int lda;
    const bf16* W; int ldw;
    const float* bias;
    void* C; int ldc; int c_fp32;
    int K; int nxb;                      // n-blocks (N / tile_n of the kernel used)
    const float* addv; long add_stride;
};

static inline GemmDesc mkdesc(const bf16* A, int lda, const bf16* W, int ldw,
                              const float* bias, void* C, int ldc, int c_fp32,
                              int K, int nxb, const float* addv, long add_stride) {
    GemmDesc d; d.A = A; d.lda = lda; d.W = W; d.ldw = ldw; d.bias = bias;
    d.C = C; d.ldc = ldc; d.c_fp32 = c_fp32; d.K = K; d.nxb = nxb;
    d.addv = addv; d.add_stride = add_stride; return d;
}

// ---------------- small MFMA GEMM (levels 4..1, root, out; 128x128) ----
__global__ __launch_bounds__(256) void gemm_dual(GemmDesc da, int na, GemmDesc db)
{
    __shared__ __align__(16) bf16 As[128 * 32];
    __shared__ __align__(16) bf16 Ws[128 * 32];
    int id = blockIdx.x;
    const bool second = (id >= na);
    if (second) id -= na;
    const GemmDesc d = second ? db : da;
    const int bm = id / d.nxb, bn = id % d.nxb;

    const int t = threadIdx.x;
    const int wave = t >> 6, lane = t & 63;
    const long m_blk = (long)bm << 7;
    const long n_blk = (long)bn << 7;

    const int srow = (wave << 5) + (lane >> 2);
    const int sbyte = (lane & 3) << 4;
    const char* gA = (const char*)(d.A + (m_blk + srow) * (long)d.lda) + sbyte;
    const char* gW = (const char*)(d.W + (n_blk + srow) * (long)d.ldw) + sbyte;
    const long aRow16 = (long)d.lda * 32;
    const long wRow16 = (long)d.ldw * 32;
    bf16* lA = As + (wave << 10);
    bf16* lW = Ws + (wave << 10);

    floatx4 zero = {0.f, 0.f, 0.f, 0.f};
    floatx4 acc[4][4];
#pragma unroll
    for (int i = 0; i < 4; i++)
#pragma unroll
        for (int j = 0; j < 4; j++) acc[i][j] = zero;

    const int mrow = (wave & 1) << 6;
    const int ncol = (wave >> 1) << 6;
    const short* AsS = (const short*)As;
    const short* WsS = (const short*)Ws;
    const int fm = lane & 15;
    const int fk = (lane >> 4) << 3;

    for (int k0 = 0; k0 < d.K; k0 += 32) {
        __builtin_amdgcn_global_load_lds(
            (const __attribute__((address_space(1))) unsigned int*)gA,
            (__attribute__((address_space(3))) unsigned int*)lA, 16, 0, 0);
        __builtin_amdgcn_global_load_lds(
            (const __attribute__((address_space(1))) unsigned int*)(gA + aRow16),
            (__attribute__((address_space(3))) unsigned int*)(lA + 512), 16, 0, 0);
        __builtin_amdgcn_global_load_lds(
            (const __attribute__((address_space(1))) unsigned int*)gW,
            (__attribute__((address_space(3))) unsigned int*)lW, 16, 0, 0);
        __builtin_amdgcn_global_load_lds(
            (const __attribute__((address_space(1))) unsigned int*)(gW + wRow16),
            (__attribute__((address_space(3))) unsigned int*)(lW + 512), 16, 0, 0);
        gA += 64; gW += 64;
        __syncthreads();

        short8 af[4], bfr[4];
#pragma unroll
        for (int i = 0; i < 4; i++) {
            af[i]  = *(const short8*)(AsS + (mrow + i * 16 + fm) * 32 + fk);
            bfr[i] = *(const short8*)(WsS + (ncol + i * 16 + fm) * 32 + fk);
        }
#pragma unroll
        for (int i = 0; i < 4; i++)
#pragma unroll
            for (int j = 0; j < 4; j++)
                acc[i][j] = __builtin_amdgcn_mfma_f32_16x16x32_bf16(
                    af[i], bfr[j], acc[i][j], 0, 0, 0);
        __syncthreads();
    }

    const int crow0 = (lane >> 4) << 2;
    const int ccol = lane & 15;
#pragma unroll
    for (int i = 0; i < 4; i++) {
#pragma unroll
        for (int j = 0; j < 4; j++) {
            const long col = n_blk + ncol + j * 16 + ccol;
            const float bv = d.bias ? d.bias[col] : 0.f;
#pragma unroll
            for (int r = 0; r < 4; r++) {
                const long row = m_blk + mrow + i * 16 + crow0 + r;
                float v = acc[i][j][r] + bv;
                if (d.addv) v += d.addv[row * d.add_stride + col];
                if (d.c_fp32) ((float*)d.C)[row * (long)d.ldc + col] = v;
                else ((bf16*)d.C)[row * (long)d.ldc + col] = __float2bfloat16(v);
            }
        }
    }
}

// ---------------- big MFMA GEMM: 256x256, BK=64, 8 waves, persistent ----
// Job queue: blocks grab job ids [0,ntot) via atomicAdd(ctr); jobs < na are
// descriptor A (long iou, first = LPT greedy), else descriptor B.
// LDS swizzle st_16x32-style: LDS[r][cb] = G[r][cb ^ ((r&7)<<4)] via
// pre-swizzled global source (write) + per-lane XOR on ds_read (read).
__global__ __launch_bounds__(512, 2) void gemm8_dual(
    GemmDesc da, int na, GemmDesc db, int ntot, unsigned int* __restrict__ ctr)
{
    __shared__ __align__(16) char smem[131072];   // A: [2][32K] @0, B @65536
    __shared__ int sjob;

    const int tid = threadIdx.x;
    const int w = tid >> 6, lane = tid & 63;

    // job-independent per-thread constants
    const int colb = (((lane & 7) ^ ((lane >> 3) & 7)) << 4);
    const int rw = (w << 4) + (lane >> 3);
    const int fm = lane & 15;
    const int fkB = (lane >> 4) << 4;
    const int sx = (lane & 7) << 4;
    const int cx0 = fkB ^ sx;
    const int cx1 = cx0 ^ 64;
    const int arow0 = ((w >> 2) << 7) + fm;       // wr*128 + fm
    const int brow0 = ((w & 3) << 6) + fm;        // wc*64 + fm
    char* lW = smem + (w << 11);

    for (;;) {
        __syncthreads();
        if (tid == 0) sjob = (int)atomicAdd(ctr, 1u);
        __syncthreads();
        int id = sjob;
        if (id >= ntot) return;
        const bool second = (id >= na);
        if (second) id -= na;
        const GemmDesc d = second ? db : da;
        const int bm = id / d.nxb, bn = id % d.nxb;
        const long m_blk = (long)bm << 8;
        const long n_blk = (long)bn << 8;
        const int T = d.K >> 6;                   // K-tiles (>=2 for all users)

        const long ldaB = (long)d.lda * 2, ldwB = (long)d.ldw * 2;
        const char* gA0 = (const char*)(d.A + m_blk * d.lda) + (long)rw * ldaB + colb;
        const char* gB0 = (const char*)(d.W + n_blk * d.ldw) + (long)rw * ldwB + colb;
        const long aH = ldaB << 7, bH = ldwB << 7;    // +128 rows (half 1)
        const long a8 = ldaB << 3, b8 = ldwB << 3;    // +8 rows (second instr)

        auto stageA = [&](int tile, int buf, int half) {
            const char* g = gA0 + (half ? aH : 0) + ((long)tile << 7);
            char* l = lW + buf * 32768 + half * 16384;
            __builtin_amdgcn_global_load_lds(
                (const __attribute__((address_space(1))) unsigned int*)g,
                (__attribute__((address_space(3))) unsigned int*)l, 16, 0, 0);
            __builtin_amdgcn_global_load_lds(
                (const __attribute__((address_space(1))) unsigned int*)(g + a8),
                (__attribute__((address_space(3))) unsigned int*)(l + 1024), 16, 0, 0);
        };
        auto stageB = [&](int tile, int buf, int half) {
            const char* g = gB0 + (half ? bH : 0) + ((long)tile << 7);
            char* l = lW + 65536 + buf * 32768 + half * 16384;
            __builtin_amdgcn_global_load_lds(
                (const __attribute__((address_space(1))) unsigned int*)g,
                (__attribute__((address_space(3))) unsigned int*)l, 16, 0, 0);
            __builtin_amdgcn_global_load_lds(
                (const __attribute__((address_space(1))) unsigned int*)(g + b8),
                (__attribute__((address_space(3))) unsigned int*)(l + 1024), 16, 0, 0);
        };

        floatx4 acc[8][4];
        const floatx4 fzero = {0.f, 0.f, 0.f, 0.f};
#pragma unroll
        for (int i = 0; i < 8; i++)
#pragma unroll
            for (int j = 0; j < 4; j++) acc[i][j] = fzero;

        // ---- prologue ----
        stageA(0, 0, 0); stageA(0, 0, 1); stageB(0, 0, 0); stageB(0, 0, 1);
        if (T > 1) {
            stageB(1, 1, 0); stageB(1, 1, 1); stageA(1, 1, 0);
            asm volatile("s_waitcnt vmcnt(6)" ::: "memory");
        } else {
            asm volatile("s_waitcnt vmcnt(0)" ::: "memory");
        }
        __builtin_amdgcn_sched_barrier(0);
        __builtin_amdgcn_s_barrier();
        __builtin_amdgcn_sched_barrier(0);

        short8 a[4][2], b[4][2];
        for (int tt = 0; tt < T; ++tt) {
            const int buf = tt & 1;
            const char* la = smem + buf * 32768;
            const char* lb = smem + 65536 + buf * 32768;
            // ---------- P1
#pragma unroll
            for (int mf = 0; mf < 4; ++mf) {
                a[mf][0] = *(const short8*)(la + ((arow0 + mf * 16) << 7) + cx0);
                a[mf][1] = *(const short8*)(la + ((arow0 + mf * 16) << 7) + cx1);
            }
#pragma unroll
            for (int nf = 0; nf < 2; ++nf) {
                b[nf][0] = *(const short8*)(lb + ((brow0 + nf * 16) << 7) + cx0);
                b[nf][1] = *(const short8*)(lb + ((brow0 + nf * 16) << 7) + cx1);
            }
            if (tt + 1 < T) stageA(tt + 1, buf ^ 1, 1);
            __builtin_amdgcn_s_barrier();
            asm volatile("s_waitcnt lgkmcnt(0)" ::: "memory");
            __builtin_amdgcn_sched_barrier(0);
            __builtin_amdgcn_s_setprio(1);
#pragma unroll
            for (int ks = 0; ks < 2; ++ks)
#pragma unroll
                for (int mf = 0; mf < 4; ++mf)
#pragma unroll
                    for (int nf = 0; nf < 2; ++nf)
                        acc[mf][nf] = __builtin_amdgcn_mfma_f32_16x16x32_bf16(
                            a[mf][ks], b[nf][ks], acc[mf][nf], 0, 0, 0);
            __builtin_amdgcn_s_setprio(0);
            __builtin_amdgcn_s_barrier();
            __builtin_amdgcn_sched_barrier(0);
            // ---------- P2
#pragma unroll
            for (int nf = 0; nf < 2; ++nf) {
                b[2 + nf][0] = *(const short8*)(lb + ((brow0 + (2 + nf) * 16) << 7) + cx0);
                b[2 + nf][1] = *(const short8*)(lb + ((brow0 + (2 + nf) * 16) << 7) + cx1);
            }
            __builtin_amdgcn_s_barrier();
            asm volatile("s_waitcnt lgkmcnt(0)" ::: "memory");
            __builtin_amdgcn_sched_barrier(0);
            __builtin_amdgcn_s_setprio(1);
#pragma unroll
            for (int ks = 0; ks < 2; ++ks)
#pragma unroll
                for (int mf = 0; mf < 4; ++mf)
#pragma unroll
                    for (int nf = 0; nf < 2; ++nf)
                        acc[mf][2 + nf] = __builtin_amdgcn_mfma_f32_16x16x32_bf16(
                            a[mf][ks], b[2 + nf][ks], acc[mf][2 + nf], 0, 0, 0);
            __builtin_amdgcn_s_setprio(0);
            __builtin_amdgcn_s_barrier();
            __builtin_amdgcn_sched_barrier(0);
            // ---------- P3
#pragma unroll
            for (int mf = 0; mf < 4; ++mf) {
                a[mf][0] = *(const short8*)(la + ((arow0 + (4 + mf) * 16) << 7) + cx0);
                a[mf][1] = *(const short8*)(la + ((arow0 + (4 + mf) * 16) << 7) + cx1);
            }
            if (tt + 2 < T) stageB(tt + 2, buf, 0);
            __builtin_amdgcn_s_barrier();
            asm volatile("s_waitcnt lgkmcnt(0)" ::: "memory");
            __builtin_amdgcn_sched_barrier(0);
            __builtin_amdgcn_s_setprio(1);
#pragma unroll
            for (int ks = 0; ks < 2; ++ks)
#pragma unroll
                for (int mf = 0; mf < 4; ++mf)
#pragma unroll
                    for (int nf = 0; nf < 2; ++nf)
                        acc[4 + mf][2 + nf] = __builtin_amdgcn_mfma_f32_16x16x32_bf16(
                            a[mf][ks], b[2 + nf][ks], acc[4 + mf][2 + nf], 0, 0, 0);
            __builtin_amdgcn_s_setprio(0);
            __builtin_amdgcn_s_barrier();
            __builtin_amdgcn_sched_barrier(0);
            // ---------- P4 (no ds reads; stages overlap MFMA)
            if (tt + 2 < T) { stageB(tt + 2, buf, 1); stageA(tt + 2, buf, 0); }
            __builtin_amdgcn_s_setprio(1);
#pragma unroll
            for (int ks = 0; ks < 2; ++ks)
#pragma unroll
                for (int mf = 0; mf < 4; ++mf)
#pragma unroll
                    for (int nf = 0; nf < 2; ++nf)
                        acc[4 + mf][nf] = __builtin_amdgcn_mfma_f32_16x16x32_bf16(
                            a[mf][ks], b[nf][ks], acc[4 + mf][nf], 0, 0, 0);
            __builtin_amdgcn_s_setprio(0);
            if (tt + 1 < T) {
                if (tt + 2 < T) asm volatile("s_waitcnt vmcnt(6)" ::: "memory");
                else            asm volatile("s_waitcnt vmcnt(0)" ::: "memory");
                __builtin_amdgcn_sched_barrier(0);
                __builtin_amdgcn_s_barrier();
                __builtin_amdgcn_sched_barrier(0);
            }
        }

        // ---------- epilogue ----------
        const int crow = (lane >> 4) << 2;
        const int ccol = lane & 15;
        const long row0 = m_blk + ((long)(w >> 2) << 7);
        const long col0 = n_blk + ((w & 3) << 6);
#pragma unroll
        for (int mf = 0; mf < 8; ++mf) {
#pragma unroll
            for (int nf = 0; nf < 4; ++nf) {
                const long col = col0 + nf * 16 + ccol;
                const float bv = d.bias ? d.bias[col] : 0.f;
#pragma unroll
                for (int r = 0; r < 4; ++r) {
                    const long row = row0 + mf * 16 + crow + r;
                    const float v = acc[mf][nf][r] + bv;
                    if (d.c_fp32) ((float*)d.C)[row * (long)d.ldc + col] = v;
                    else ((bf16*)d.C)[row * (long)d.ldc + col] = __float2bfloat16(v);
                }
            }
        }
    }
}

// ---------------- pointwise ----------------
__device__ inline float sigf(float x) { return 1.f / (1.f + __expf(-x)); }
__device__ inline float tanh_fast(float x) { return 2.f / (1.f + __expf(-2.f * x)) - 1.f; }

__device__ inline void block_reduce4(float& a, float& b, float& c, float& d,
                                     float* s) {
#pragma unroll
    for (int off = 32; off > 0; off >>= 1) {
        a += __shfl_down(a, off, 64);
        b += __shfl_down(b, off, 64);
        c += __shfl_down(c, off, 64);
        d += __shfl_down(d, off, 64);
    }
    const int lane = threadIdx.x & 63, w = threadIdx.x >> 6;
    __syncthreads();
    if (lane == 0) { s[w] = a; s[w + 4] = b; s[w + 8] = c; s[w + 12] = d; }
    __syncthreads();
    a = s[0] + s[1] + s[2] + s[3];
    b = s[4] + s[5] + s[6] + s[7];
    c = s[8] + s[9] + s[10] + s[11];
    d = s[12] + s[13] + s[14] + s[15];
}

// Block handles sibling rows 2p,2p+1 (chunk-local). 192 active lanes x 4
// contiguous cols (ushort4/float4 loads). Writes h rows and the next level's
// A_cat row [xs | h0+h1] at parent index.
__global__ __launch_bounds__(256) void pointwise_pair(
    const bf16* __restrict__ C, int ldc,
    const bf16* __restrict__ fhb,
    const bf16* __restrict__ hprev2,
    const float* __restrict__ x,
    const float* __restrict__ bfh,
    const float* __restrict__ gc, const float* __restrict__ bc,
    const float* __restrict__ gh, const float* __restrict__ bh,
    bf16* __restrict__ hout,
    bf16* __restrict__ Anext,
    int m0, int lp)
{
    __shared__ float sred[16];
    const int pl = blockIdx.x;
    const int t = threadIdx.x;
    const bool act = t < 192;
    const int j = t << 2;                       // col base (act only)
    const bf16* cr0 = C + (long)(2 * pl) * ldc;
    const bf16* cr1 = cr0 + ldc;
    float c0v[4], c1v[4], o0v[4], o1v[4], h0v[4], h1v[4];
    float s0 = 0.f, q0 = 0.f, s1 = 0.f, q1 = 0.f;
    if (act) {
        float i0[4], i1[4], u0[4], u1[4];
        ld4(cr0 + j, i0); ld4(cr1 + j, i1);
        ld4(cr0 + Hdim + j, o0v); ld4(cr1 + Hdim + j, o1v);
        ld4(cr0 + 2 * Hdim + j, u0); ld4(cr1 + 2 * Hdim + j, u1);
        if (fhb) {
            float fx0[4], fx1[4], fb0[4], fb1[4], fb2[4], fb3[4];
            float hp0[4], hp1[4], hp2[4], hp3[4];
            ld4(cr0 + 3 * Hdim + j, fx0); ld4(cr1 + 3 * Hdim + j, fx1);
            const long base = (long)(4 * pl) * Hdim + j;
            ld4(fhb + base, fb0); ld4(fhb + base + Hdim, fb1);
            ld4(fhb + base + 2 * Hdim, fb2); ld4(fhb + base + 3 * Hdim, fb3);
            ld4(hprev2 + base, hp0); ld4(hprev2 + base + Hdim, hp1);
            ld4(hprev2 + base + 2 * Hdim, hp2); ld4(hprev2 + base + 3 * Hdim, hp3);
            const float4 bf4 = *(const float4*)(bfh + j);
#pragma unroll
            for (int q = 0; q < 4; q++) {
                const float bq = (&bf4.x)[q];
                float c0 = sigf(i0[q]) * tanh_fast(u0[q]);
                float c1 = sigf(i1[q]) * tanh_fast(u1[q]);
                c0 += sigf(fx0[q] + fb0[q] + bq) * hp0[q]
                    + sigf(fx0[q] + fb1[q] + bq) * hp1[q];
                c1 += sigf(fx1[q] + fb2[q] + bq) * hp2[q]
                    + sigf(fx1[q] + fb3[q] + bq) * hp3[q];
                c0v[q] = c0; c1v[q] = c1;
                s0 += c0; q0 += c0 * c0; s1 += c1; q1 += c1 * c1;
            }
        } else {
#pragma unroll
            for (int q = 0; q < 4; q++) {
                const float c0 = sigf(i0[q]) * tanh_fast(u0[q]);
                const float c1 = sigf(i1[q]) * tanh_fast(u1[q]);
                c0v[q] = c0; c1v[q] = c1;
                s0 += c0; q0 += c0 * c0; s1 += c1; q1 += c1 * c1;
            }
        }
    }
    block_reduce4(s0, q0, s1, q1, sred);
    const float m0c = s0 / Hdim, m1c = s1 / Hdim;
    const float r0c = rsqrtf(q0 / Hdim - m0c * m0c + 1e-5f);
    const float r1c = rsqrtf(q1 / Hdim - m1c * m1c + 1e-5f);
    float hs0 = 0.f, hq0 = 0.f, hs1 = 0.f, hq1 = 0.f;
    if (act) {
        const float4 gc4 = *(const float4*)(gc + j);
        const float4 bc4 = *(const float4*)(bc + j);
#pragma unroll
        for (int q = 0; q < 4; q++) {
            const float cn0 = (c0v[q] - m0c) * r0c * (&gc4.x)[q] + (&bc4.x)[q];
            const float cn1 = (c1v[q] - m1c) * r1c * (&gc4.x)[q] + (&bc4.x)[q];
            const float h0 = sigf(o0v[q]) * tanh_fast(cn0);
            const float h1 = sigf(o1v[q]) * tanh_fast(cn1);
            h0v[q] = h0; h1v[q] = h1;
            hs0 += h0; hq0 += h0 * h0; hs1 += h1; hq1 += h1 * h1;
        }
    }
    block_reduce4(hs0, hq0, hs1, hq1, sred);
    const float mh0 = hs0 / Hdim, mh1 = hs1 / Hdim;
    const float rh0 = rsqrtf(hq0 / Hdim - mh0 * mh0 + 1e-5f);
    const float rh1 = rsqrtf(hq1 / Hdim - mh1 * mh1 + 1e-5f);

    if (act) {
        const int pg = m0 / 2 + pl;
        const int b = pg >> lp;
        const int jn = pg & ((1 << lp) - 1);
        const float* xr = x + ((long)b * 255 + (1 << lp) - 1 + jn) * Hdim;
        bf16* arow = Anext + (long)pg * 1536;
        const float4 gh4 = *(const float4*)(gh + j);
        const float4 bh4 = *(const float4*)(bh + j);
        const float4 xr4 = *(const float4*)(xr + j);
        float hh0[4], hh1[4], ha[4], xs[4];
#pragma unroll
        for (int q = 0; q < 4; q++) {
            hh0[q] = (h0v[q] - mh0) * rh0 * (&gh4.x)[q] + (&bh4.x)[q];
            hh1[q] = (h1v[q] - mh1) * rh1 * (&gh4.x)[q] + (&bh4.x)[q];
            ha[q] = hh0[q] + hh1[q];
            xs[q] = (&xr4.x)[q];
        }
        st4(hout + (long)(2 * pl) * Hdim + j, hh0);
        st4(hout + (long)(2 * pl + 1) * Hdim + j, hh1);
        st4(arow + 768 + j, ha);
        st4(arow + j, xs);
    }
}

__global__ __launch_bounds__(256) void pointwise_root(
    const bf16* __restrict__ C, int ldc,
    const bf16* __restrict__ fhb, const bf16* __restrict__ hprev,
    const float* __restrict__ bfh,
    const float* __restrict__ gc, const float* __restrict__ bc,
    const float* __restrict__ gh, const float* __restrict__ bh,
    bf16* __restrict__ hout)
{
    __shared__ float sred[16];
    const int m = blockIdx.x;
    const int t = threadIdx.x;
    const bool act = t < 192;
    const int j = t << 2;
    const bf16* cr = C + (long)m * ldc;
    float cv[4], ov[4], hv[4];
    float ssum = 0.f, ssq = 0.f, d0 = 0.f, d1 = 0.f;
    if (act) {
        float iv[4], uv[4], fx[4], fb0[4], fb1[4], hp0[4], hp1[4];
        ld4(cr + j, iv); ld4(cr + Hdim + j, ov); ld4(cr + 2 * Hdim + j, uv);
        ld4(cr + 3 * Hdim + j, fx);
        const long base = (long)(2 * m) * Hdim + j;
        ld4(fhb + base, fb0); ld4(fhb + base + Hdim, fb1);
        ld4(hprev + base, hp0); ld4(hprev + base + Hdim, hp1);
        const float4 bf4 = *(const float4*)(bfh + j);
#pragma unroll
        for (int q = 0; q < 4; q++) {
            const float bq = (&bf4.x)[q];
            float c = sigf(iv[q]) * tanh_fast(uv[q]);
            c += sigf(fx[q] + fb0[q] + bq) * hp0[q]
               + sigf(fx[q] + fb1[q] + bq) * hp1[q];
            cv[q] = c; ssum += c; ssq += c * c;
        }
    }
    block_reduce4(ssum, ssq, d0, d1, sred);
    const float mean = ssum / Hdim;
    const float rstd = rsqrtf(ssq / Hdim - mean * mean + 1e-5f);
    float hs = 0.f, hq = 0.f;
    if (act) {
        const float4 gc4 = *(const float4*)(gc + j);
        const float4 bc4 = *(const float4*)(bc + j);
#pragma unroll
        for (int q = 0; q < 4; q++) {
            const float cn = (cv[q] - mean) * rstd * (&gc4.x)[q] + (&bc4.x)[q];
            const float h = sigf(ov[q]) * tanh_fast(cn);
            hv[q] = h; hs += h; hq += h * h;
        }
    }
    d0 = 0.f; d1 = 0.f;
    block_reduce4(hs, hq, d0, d1, sred);
    const float mh = hs / Hdim;
    const float rh = rsqrtf(hq / Hdim - mh * mh + 1e-5f);
    if (act) {
        const float4 gh4 = *(const float4*)(gh + j);
        const float4 bh4 = *(const float4*)(bh + j);
        float hh[4];
#pragma unroll
        for (int q = 0; q < 4; q++)
            hh[q] = (hv[q] - mh) * rh * (&gh4.x)[q] + (&bh4.x)[q];
        st4(hout + (long)m * Hdim + j, hh);
    }
}

// ---------------- launch ----------------
extern "C" void kernel_launch(void* const* d_in, const int* in_sizes, int n_in,
                              void* d_out, int out_size, void* d_ws, size_t ws_size,
                              hipStream_t stream) {
    (void)in_sizes; (void)n_in; (void)out_size; (void)ws_size;
    const float* x      = (const float*)d_in[0];
    const float* Wioux  = (const float*)d_in[1];
    const float* b_ioux = (const float*)d_in[2];
    const float* Wiouh  = (const float*)d_in[3];
    const float* Wfx    = (const float*)d_in[4];
    const float* b_fx   = (const float*)d_in[5];
    const float* Wfh    = (const float*)d_in[6];
    const float* b_fh   = (const float*)d_in[7];
    const float* ln_c_g = (const float*)d_in[8];
    const float* ln_c_b = (const float*)d_in[9];
    const float* ln_h_g = (const float*)d_in[10];
    const float* ln_h_b = (const float*)d_in[11];
    const float* Wout   = (const float*)d_in[12];
    const float* b_out  = (const float*)d_in[13];
    float* out = (float*)d_out;

    // ---- workspace (~212 MB) ----
    char* p = (char*)d_ws;
    bf16* W_cat   = (bf16*)p; p += 8L * 3072 * 1536 * 2;   // 75.5 MB
    bf16* Wfh_bf  = (bf16*)p; p += 8L * 768 * 768 * 2;     //  9.4 MB
    bf16* Wout_bf = (bf16*)p; p += 768L * 768 * 2;         //  1.2 MB
    float* b_cat  = (float*)p; p += 8L * 3072 * 4;         //  0.1 MB
    bf16* leafA   = (bf16*)p; p += 16384L * 768 * 2;       // 25.2 MB (fhb overlay)
    bf16* A6      = (bf16*)p; p += 8192L * 1536 * 2;       // 25.2 MB
    bf16* A5      = (bf16*)p; p += 4096L * 1536 * 2;       // 12.6 MB
    bf16* Cbuf    = (bf16*)p; p += 4096L * 3072 * 2;       // 25.2 MB
    bf16* hA      = (bf16*)p; p += 16384L * 768 * 2;       // 25.2 MB
    bf16* hB      = (bf16*)p; p += 8192L * 768 * 2;        // 12.6 MB
    unsigned int* ctrs = (unsigned int*)p; p += 64;        // job counters
    bf16* fhb     = leafA;  // leafA dead once leaf GEMMs complete
    bf16* Cleaf   = A5;     // A5+Cbuf contiguous = 8192*2304*2 bytes capacity

    // ---- prep (2 launches; prep_misc also zeroes job counters) ----
    conv_wcat<<<8 * 3072, 384, 0, stream>>>(Wioux, Wiouh, Wfx, W_cat);
    prep_misc<<<5280 + 16384 + 1, 256, 0, stream>>>(
        Wfh, Wout, b_ioux, b_fx, x, Wfh_bf, Wout_bf, b_cat, leafA, ctrs);

    GemmDesc dummy = mkdesc(nullptr, 0, nullptr, 0, nullptr, nullptr, 0, 0, 0, 1,
                            nullptr, 0);
    int kc = 0;   // counter index

    // ---- leaf level l=7: 3 chunks, each <=256 jobs => makespan ~1 block ----
    {
        const int cm0[3] = {0, 5632, 11264};
        const int cmc[3] = {5632, 5632, 5120};
        for (int c = 0; c < 3; c++) {
            const int m0 = cm0[c], Mc = cmc[c];
            GemmDesc dl = mkdesc(leafA + (long)m0 * 768, 768,
                                 W_cat + 7L * 3072 * 1536, 1536, b_cat + 7 * 3072,
                                 Cleaf, 2304, 0, 768, 9, nullptr, 0);
            const int ntot = (Mc / 256) * 9;
            gemm8_dual<<<(ntot < 256 ? ntot : 256), 512, 0, stream>>>(
                dl, ntot, dummy, ntot, ctrs + kc++);
            pointwise_pair<<<Mc / 2, 256, 0, stream>>>(
                Cleaf, 2304, nullptr, nullptr, x, nullptr,
                ln_c_g + 7 * Hdim, ln_c_b + 7 * Hdim, ln_h_g + 7 * Hdim, ln_h_b + 7 * Hdim,
                hA + (long)m0 * Hdim, A6, m0, 6);
        }
    }

    // ---- levels 6..1 ----
    const int CH = 4096;
    bf16* hp = hA; bf16* hc = hB;
    bf16* Acur = A6; bf16* Anxt = A5;
    for (int l = 6; l >= 1; l--) {
        const int M = 128 << l;
        const int Mc = (M < CH) ? M : CH;
        const int nch = M / Mc;
        for (int c = 0; c < nch; c++) {
            const int m0 = c * Mc;
            if (l >= 5) {
                // persistent 256^2 kernel; per-chunk fh (balanced 2:1 mix)
                GemmDesc diou = mkdesc(Acur + (long)m0 * 1536, 1536,
                                       W_cat + (long)l * 3072 * 1536, 1536,
                                       b_cat + l * 3072, Cbuf, 3072, 0, 1536, 12,
                                       nullptr, 0);
                GemmDesc dfh = mkdesc(hp + (long)2 * m0 * Hdim, 768,
                                      Wfh_bf + (long)l * 768 * 768, 768, nullptr,
                                      fhb, 768, 0, 768, 3, nullptr, 0);
                const int na = 12 * (Mc / 256);
                const int nb = 3 * (2 * Mc / 256);
                const int ntot = na + nb;
                gemm8_dual<<<(ntot < 256 ? ntot : 256), 512, 0, stream>>>(
                    diou, na, dfh, ntot, ctrs + kc++);
            } else {
                // many small 128^2 blocks; ~6 blocks/CU co-resident
                GemmDesc diou = mkdesc(Acur + (long)m0 * 1536, 1536,
                                       W_cat + (long)l * 3072 * 1536, 1536,
                                       b_cat + l * 3072, Cbuf, 3072, 0, 1536, 24,
                                       nullptr, 0);
                GemmDesc dfh = mkdesc(hp + (long)2 * m0 * Hdim, 768,
                                      Wfh_bf + (long)l * 768 * 768, 768, nullptr,
                                      fhb, 768, 0, 768, 6, nullptr, 0);
                const int na = 24 * (Mc / 128);
                const int nb = 6 * (2 * Mc / 128);
                gemm_dual<<<na + nb, 256, 0, stream>>>(diou, na, dfh);
            }
            pointwise_pair<<<Mc / 2, 256, 0, stream>>>(
                Cbuf, 3072, fhb, hp + (long)2 * m0 * Hdim, x, b_fh + l * Hdim,
                ln_c_g + l * Hdim, ln_c_b + l * Hdim, ln_h_g + l * Hdim, ln_h_b + l * Hdim,
                hc + (long)m0 * Hdim, Anxt, m0, l - 1);
        }
        bf16* t1 = hp; hp = hc; hc = t1;
        bf16* t2 = Acur; Acur = Anxt; Anxt = t2;
    }

    // ---- root level l=0 (M=128, 128^2 kernel) ----
    {
        GemmDesc diou = mkdesc(Acur, 1536, W_cat, 1536, b_cat, Cbuf, 3072, 0,
                               1536, 24, nullptr, 0);
        GemmDesc dfh = mkdesc(hp, 768, Wfh_bf, 768, nullptr, fhb, 768, 0,
                              768, 6, nullptr, 0);
        gemm_dual<<<24 + 12, 256, 0, stream>>>(diou, 24, dfh);
        pointwise_root<<<128, 256, 0, stream>>>(
            Cbuf, 3072, fhb, hp, b_fh,
            ln_c_g, ln_c_b, ln_h_g, ln_h_b, hc);
    }

    // ---- out = h_root @ Wout^T + b_out + x[:,0] ----
    {
        GemmDesc dout = mkdesc(hc, 768, Wout_bf, 768, b_out, out, 768, 1,
                               768, 6, x, 255L * 768);
        gemm_dual<<<6, 256, 0, stream>>>(dout, 6, dummy);
    }
}

// Round 4
// 894.986 us; speedup vs baseline: 1.1853x; 1.1062x over previous
//
#include <hip/hip_runtime.h>
#include <hip/hip_bf16.h>

// TreeLSTM (child-sum, complete binary tree, DEPTH=8) on MI355X.
// Round 8: split-K for all small GEMMs. R3 lesson: 128^2 gemm_dual is
// latency-bound (~1.9us per 32-K-step => K=1536 block = ~90us); levels 4..1
// + root + out were ~500us of latency. GemmDesc gains nps/cslice: blocks
// decode a K-slice s, write bf16 partial slabs (slice0 carries bias);
// pointwise sums slices. out uses fp32 partials + out_reduce (b_out+x fused).
// Leaf/l6/l5 keep the persistent 256^2 8-phase gemm8 (queue, LDS swizzle).

#define Hdim 768

typedef __hip_bfloat16 bf16;
typedef __attribute__((ext_vector_type(8))) short short8;
typedef __attribute__((ext_vector_type(4))) float floatx4;

__device__ inline float b2f(unsigned short u) {
    union { unsigned int i; float f; } v; v.i = ((unsigned int)u) << 16; return v.f;
}
__device__ inline float b2f(bf16 h) { return b2f(*(unsigned short*)&h); }
__device__ inline unsigned short f2bu(float f) {
    bf16 h = __float2bfloat16(f);
    return *(unsigned short*)&h;
}
__device__ inline ushort4 cvt4(float4 v) {
    ushort4 o; o.x = f2bu(v.x); o.y = f2bu(v.y); o.z = f2bu(v.z); o.w = f2bu(v.w);
    return o;
}
__device__ inline void ld4(const bf16* p, float* o) {
    ushort4 u = *(const ushort4*)p;
    o[0] = b2f(u.x); o[1] = b2f(u.y); o[2] = b2f(u.z); o[3] = b2f(u.w);
}
__device__ inline void st4(bf16* p, const float* v) {
    ushort4 u; u.x = f2bu(v[0]); u.y = f2bu(v[1]); u.z = f2bu(v[2]); u.w = f2bu(v[3]);
    *(ushort4*)p = u;
}

// ---------------- weight prep ----------------
// W_cat[l] : [3072][1536] = [[Wioux[l] | Wiouh[l]]; [Wfx[l] | 0]]
__global__ __launch_bounds__(384) void conv_wcat(
    const float* __restrict__ Wioux, const float* __restrict__ Wiouh,
    const float* __restrict__ Wfx, bf16* __restrict__ W_cat)
{
    const int row = blockIdx.x;          // 0 .. 8*3072-1
    const int l = row / 3072;
    const int g = row % 3072;
    const int t = threadIdx.x;
    const int k2 = t << 2;
    float4 v;
    if (g < 2304) {
        const float* src = (k2 < 768)
            ? Wioux + ((long)l * 2304 + g) * 768 + k2
            : Wiouh + ((long)l * 2304 + g) * 768 + (k2 - 768);
        v = *(const float4*)src;
    } else if (k2 < 768) {
        v = *(const float4*)(Wfx + ((long)l * 768 + (g - 2304)) * 768 + k2);
    } else {
        v = make_float4(0.f, 0.f, 0.f, 0.f);
    }
    ((ushort4*)(W_cat + (long)row * 1536))[t] = cvt4(v);
}

// Merged prep: Wfh f2b [0,4608) | Wout f2b [4608,5184) | b_cat [5184,5280)
//            | leaf conv [5280, 5280+16384) | job counters [21664]
__global__ __launch_bounds__(256) void prep_misc(
    const float* __restrict__ Wfh, const float* __restrict__ Wout,
    const float* __restrict__ b_ioux, const float* __restrict__ b_fx,
    const float* __restrict__ x,
    bf16* __restrict__ Wfh_bf, bf16* __restrict__ Wout_bf,
    float* __restrict__ b_cat, bf16* __restrict__ leafA,
    unsigned int* __restrict__ ctrs)
{
    const int id = blockIdx.x;
    const int t = threadIdx.x;
    if (id < 4608) {
        const long i = (long)id * 256 + t;
        ((ushort4*)Wfh_bf)[i] = cvt4(((const float4*)Wfh)[i]);
    } else if (id < 5184) {
        const long i = (long)(id - 4608) * 256 + t;
        ((ushort4*)Wout_bf)[i] = cvt4(((const float4*)Wout)[i]);
    } else if (id < 5280) {
        const int i = (id - 5184) * 256 + t;   // 0..24575
        const int l = i / 3072, g = i % 3072;
        b_cat[i] = (g < 2304) ? b_ioux[l * 2304 + g] : b_fx[l * 768 + (g - 2304)];
    } else if (id < 21664) {
        if (t < 192) {
            const int m = id - 5280;           // 0..16383
            const int b = m >> 7, j = m & 127;
            const float* xr = x + ((long)b * 255 + 127 + j) * Hdim;
            ((ushort4*)(leafA + (long)m * Hdim))[t] = cvt4(((const float4*)xr)[t]);
        }
    } else {
        if (t < 16) ctrs[t] = 0;               // persistent-GEMM job counters
    }
}

// ---------------- GEMM descriptors ----------------
struct GemmDesc {
    const bf16* A; int lda;
    const bf16* W; int ldw;
    const float* bias;
    void* C; int ldc; int c_fp32;
    int K;                               // K per slice
    int nxb;                             // n-blocks per slice row
    const float* addv; long add_stride;
    int nps;                             // blocks per K-slice
    long cslice;                         // C slice stride in BYTES
};

static inline GemmDesc mkdesc(const bf16* A, int lda, const bf16* W, int ldw,
                              const float* bias, void* C, int ldc, int c_fp32,
                              int K, int nxb, const float* addv, long add_stride,
                              int nps, long cslice) {
    GemmDesc d; d.A = A; d.lda = lda; d.W = W; d.ldw = ldw; d.bias = bias;
    d.C = C; d.ldc = ldc; d.c_fp32 = c_fp32; d.K = K; d.nxb = nxb;
    d.addv = addv; d.add_stride = add_stride; d.nps = nps; d.cslice = cslice;
    return d;
}

// ---------------- small MFMA GEMM with split-K (128x128 tile) ----------------
// Block id decodes (slice s, bm, bn); computes A[:,sK:(s+1)K]@W[:,sK:..]^T
// into C + s*cslice. Slice 0 carries the bias.
__global__ __launch_bounds__(256) void gemm_dual(GemmDesc da, int na, GemmDesc db)
{
    __shared__ __align__(16) bf16 As[128 * 32];
    __shared__ __align__(16) bf16 Ws[128 * 32];
    int id = blockIdx.x;
    const bool second = (id >= na);
    if (second) id -= na;
    const GemmDesc d = second ? db : da;
    const int s = id / d.nps; id -= s * d.nps;
    const int bm = id / d.nxb, bn = id % d.nxb;
    const bf16* Ag = d.A + (long)s * d.K;
    const bf16* Wg = d.W + (long)s * d.K;
    char* Cg = (char*)d.C + (long)s * d.cslice;
    const float* bias = (s == 0) ? d.bias : nullptr;

    const int t = threadIdx.x;
    const int wave = t >> 6, lane = t & 63;
    const long m_blk = (long)bm << 7;
    const long n_blk = (long)bn << 7;

    const int srow = (wave << 5) + (lane >> 2);
    const int sbyte = (lane & 3) << 4;
    const char* gA = (const char*)(Ag + (m_blk + srow) * (long)d.lda) + sbyte;
    const char* gW = (const char*)(Wg + (n_blk + srow) * (long)d.ldw) + sbyte;
    const long aRow16 = (long)d.lda * 32;
    const long wRow16 = (long)d.ldw * 32;
    bf16* lA = As + (wave << 10);
    bf16* lW = Ws + (wave << 10);

    floatx4 zero = {0.f, 0.f, 0.f, 0.f};
    floatx4 acc[4][4];
#pragma unroll
    for (int i = 0; i < 4; i++)
#pragma unroll
        for (int j = 0; j < 4; j++) acc[i][j] = zero;

    const int mrow = (wave & 1) << 6;
    const int ncol = (wave >> 1) << 6;
    const short* AsS = (const short*)As;
    const short* WsS = (const short*)Ws;
    const int fm = lane & 15;
    const int fk = (lane >> 4) << 3;

    for (int k0 = 0; k0 < d.K; k0 += 32) {
        __builtin_amdgcn_global_load_lds(
            (const __attribute__((address_space(1))) unsigned int*)gA,
            (__attribute__((address_space(3))) unsigned int*)lA, 16, 0, 0);
        __builtin_amdgcn_global_load_lds(
            (const __attribute__((address_space(1))) unsigned int*)(gA + aRow16),
            (__attribute__((address_space(3))) unsigned int*)(lA + 512), 16, 0, 0);
        __builtin_amdgcn_global_load_lds(
            (const __attribute__((address_space(1))) unsigned int*)gW,
            (__attribute__((address_space(3))) unsigned int*)lW, 16, 0, 0);
        __builtin_amdgcn_global_load_lds(
            (const __attribute__((address_space(1))) unsigned int*)(gW + wRow16),
            (__attribute__((address_space(3))) unsigned int*)(lW + 512), 16, 0, 0);
        gA += 64; gW += 64;
        __syncthreads();

        short8 af[4], bfr[4];
#pragma unroll
        for (int i = 0; i < 4; i++) {
            af[i]  = *(const short8*)(AsS + (mrow + i * 16 + fm) * 32 + fk);
            bfr[i] = *(const short8*)(WsS + (ncol + i * 16 + fm) * 32 + fk);
        }
#pragma unroll
        for (int i = 0; i < 4; i++)
#pragma unroll
            for (int j = 0; j < 4; j++)
                acc[i][j] = __builtin_amdgcn_mfma_f32_16x16x32_bf16(
                    af[i], bfr[j], acc[i][j], 0, 0, 0);
        __syncthreads();
    }

    const int crow0 = (lane >> 4) << 2;
    const int ccol = lane & 15;
#pragma unroll
    for (int i = 0; i < 4; i++) {
#pragma unroll
        for (int j = 0; j < 4; j++) {
            const long col = n_blk + ncol + j * 16 + ccol;
            const float bv = bias ? bias[col] : 0.f;
#pragma unroll
            for (int r = 0; r < 4; r++) {
                const long row = m_blk + mrow + i * 16 + crow0 + r;
                float v = acc[i][j][r] + bv;
                if (d.addv) v += d.addv[row * d.add_stride + col];
                if (d.c_fp32) ((float*)Cg)[row * (long)d.ldc + col] = v;
                else ((bf16*)Cg)[row * (long)d.ldc + col] = __float2bfloat16(v);
            }
        }
    }
}

// ---------------- big MFMA GEMM: 256x256, BK=64, 8 waves, persistent ----
__global__ __launch_bounds__(512, 2) void gemm8_dual(
    GemmDesc da, int na, GemmDesc db, int ntot, unsigned int* __restrict__ ctr)
{
    __shared__ __align__(16) char smem[131072];   // A: [2][32K] @0, B @65536
    __shared__ int sjob;

    const int tid = threadIdx.x;
    const int w = tid >> 6, lane = tid & 63;

    const int colb = (((lane & 7) ^ ((lane >> 3) & 7)) << 4);
    const int rw = (w << 4) + (lane >> 3);
    const int fm = lane & 15;
    const int fkB = (lane >> 4) << 4;
    const int sx = (lane & 7) << 4;
    const int cx0 = fkB ^ sx;
    const int cx1 = cx0 ^ 64;
    const int arow0 = ((w >> 2) << 7) + fm;       // wr*128 + fm
    const int brow0 = ((w & 3) << 6) + fm;        // wc*64 + fm
    char* lW = smem + (w << 11);

    for (;;) {
        __syncthreads();
        if (tid == 0) sjob = (int)atomicAdd(ctr, 1u);
        __syncthreads();
        int id = sjob;
        if (id >= ntot) return;
        const bool second = (id >= na);
        if (second) id -= na;
        const GemmDesc d = second ? db : da;
        const int bm = id / d.nxb, bn = id % d.nxb;
        const long m_blk = (long)bm << 8;
        const long n_blk = (long)bn << 8;
        const int T = d.K >> 6;

        const long ldaB = (long)d.lda * 2, ldwB = (long)d.ldw * 2;
        const char* gA0 = (const char*)(d.A + m_blk * d.lda) + (long)rw * ldaB + colb;
        const char* gB0 = (const char*)(d.W + n_blk * d.ldw) + (long)rw * ldwB + colb;
        const long aH = ldaB << 7, bH = ldwB << 7;
        const long a8 = ldaB << 3, b8 = ldwB << 3;

        auto stageA = [&](int tile, int buf, int half) {
            const char* g = gA0 + (half ? aH : 0) + ((long)tile << 7);
            char* l = lW + buf * 32768 + half * 16384;
            __builtin_amdgcn_global_load_lds(
                (const __attribute__((address_space(1))) unsigned int*)g,
                (__attribute__((address_space(3))) unsigned int*)l, 16, 0, 0);
            __builtin_amdgcn_global_load_lds(
                (const __attribute__((address_space(1))) unsigned int*)(g + a8),
                (__attribute__((address_space(3))) unsigned int*)(l + 1024), 16, 0, 0);
        };
        auto stageB = [&](int tile, int buf, int half) {
            const char* g = gB0 + (half ? bH : 0) + ((long)tile << 7);
            char* l = lW + 65536 + buf * 32768 + half * 16384;
            __builtin_amdgcn_global_load_lds(
                (const __attribute__((address_space(1))) unsigned int*)g,
                (__attribute__((address_space(3))) unsigned int*)l, 16, 0, 0);
            __builtin_amdgcn_global_load_lds(
                (const __attribute__((address_space(1))) unsigned int*)(g + b8),
                (__attribute__((address_space(3))) unsigned int*)(l + 1024), 16, 0, 0);
        };

        floatx4 acc[8][4];
        const floatx4 fzero = {0.f, 0.f, 0.f, 0.f};
#pragma unroll
        for (int i = 0; i < 8; i++)
#pragma unroll
            for (int j = 0; j < 4; j++) acc[i][j] = fzero;

        stageA(0, 0, 0); stageA(0, 0, 1); stageB(0, 0, 0); stageB(0, 0, 1);
        if (T > 1) {
            stageB(1, 1, 0); stageB(1, 1, 1); stageA(1, 1, 0);
            asm volatile("s_waitcnt vmcnt(6)" ::: "memory");
        } else {
            asm volatile("s_waitcnt vmcnt(0)" ::: "memory");
        }
        __builtin_amdgcn_sched_barrier(0);
        __builtin_amdgcn_s_barrier();
        __builtin_amdgcn_sched_barrier(0);

        short8 a[4][2], b[4][2];
        for (int tt = 0; tt < T; ++tt) {
            const int buf = tt & 1;
            const char* la = smem + buf * 32768;
            const char* lb = smem + 65536 + buf * 32768;
            // ---------- P1
#pragma unroll
            for (int mf = 0; mf < 4; ++mf) {
                a[mf][0] = *(const short8*)(la + ((arow0 + mf * 16) << 7) + cx0);
                a[mf][1] = *(const short8*)(la + ((arow0 + mf * 16) << 7) + cx1);
            }
#pragma unroll
            for (int nf = 0; nf < 2; ++nf) {
                b[nf][0] = *(const short8*)(lb + ((brow0 + nf * 16) << 7) + cx0);
                b[nf][1] = *(const short8*)(lb + ((brow0 + nf * 16) << 7) + cx1);
            }
            if (tt + 1 < T) stageA(tt + 1, buf ^ 1, 1);
            __builtin_amdgcn_s_barrier();
            asm volatile("s_waitcnt lgkmcnt(0)" ::: "memory");
            __builtin_amdgcn_sched_barrier(0);
            __builtin_amdgcn_s_setprio(1);
#pragma unroll
            for (int ks = 0; ks < 2; ++ks)
#pragma unroll
                for (int mf = 0; mf < 4; ++mf)
#pragma unroll
                    for (int nf = 0; nf < 2; ++nf)
                        acc[mf][nf] = __builtin_amdgcn_mfma_f32_16x16x32_bf16(
                            a[mf][ks], b[nf][ks], acc[mf][nf], 0, 0, 0);
            __builtin_amdgcn_s_setprio(0);
            __builtin_amdgcn_s_barrier();
            __builtin_amdgcn_sched_barrier(0);
            // ---------- P2
#pragma unroll
            for (int nf = 0; nf < 2; ++nf) {
                b[2 + nf][0] = *(const short8*)(lb + ((brow0 + (2 + nf) * 16) << 7) + cx0);
                b[2 + nf][1] = *(const short8*)(lb + ((brow0 + (2 + nf) * 16) << 7) + cx1);
            }
            __builtin_amdgcn_s_barrier();
            asm volatile("s_waitcnt lgkmcnt(0)" ::: "memory");
            __builtin_amdgcn_sched_barrier(0);
            __builtin_amdgcn_s_setprio(1);
#pragma unroll
            for (int ks = 0; ks < 2; ++ks)
#pragma unroll
                for (int mf = 0; mf < 4; ++mf)
#pragma unroll
                    for (int nf = 0; nf < 2; ++nf)
                        acc[mf][2 + nf] = __builtin_amdgcn_mfma_f32_16x16x32_bf16(
                            a[mf][ks], b[2 + nf][ks], acc[mf][2 + nf], 0, 0, 0);
            __builtin_amdgcn_s_setprio(0);
            __builtin_amdgcn_s_barrier();
            __builtin_amdgcn_sched_barrier(0);
            // ---------- P3
#pragma unroll
            for (int mf = 0; mf < 4; ++mf) {
                a[mf][0] = *(const short8*)(la + ((arow0 + (4 + mf) * 16) << 7) + cx0);
                a[mf][1] = *(const short8*)(la + ((arow0 + (4 + mf) * 16) << 7) + cx1);
            }
            if (tt + 2 < T) stageB(tt + 2, buf, 0);
            __builtin_amdgcn_s_barrier();
            asm volatile("s_waitcnt lgkmcnt(0)" ::: "memory");
            __builtin_amdgcn_sched_barrier(0);
            __builtin_amdgcn_s_setprio(1);
#pragma unroll
            for (int ks = 0; ks < 2; ++ks)
#pragma unroll
                for (int mf = 0; mf < 4; ++mf)
#pragma unroll
                    for (int nf = 0; nf < 2; ++nf)
                        acc[4 + mf][2 + nf] = __builtin_amdgcn_mfma_f32_16x16x32_bf16(
                            a[mf][ks], b[2 + nf][ks], acc[4 + mf][2 + nf], 0, 0, 0);
            __builtin_amdgcn_s_setprio(0);
            __builtin_amdgcn_s_barrier();
            __builtin_amdgcn_sched_barrier(0);
            // ---------- P4
            if (tt + 2 < T) { stageB(tt + 2, buf, 1); stageA(tt + 2, buf, 0); }
            __builtin_amdgcn_s_setprio(1);
#pragma unroll
            for (int ks = 0; ks < 2; ++ks)
#pragma unroll
                for (int mf = 0; mf < 4; ++mf)
#pragma unroll
                    for (int nf = 0; nf < 2; ++nf)
                        acc[4 + mf][nf] = __builtin_amdgcn_mfma_f32_16x16x32_bf16(
                            a[mf][ks], b[nf][ks], acc[4 + mf][nf], 0, 0, 0);
            __builtin_amdgcn_s_setprio(0);
            if (tt + 1 < T) {
                if (tt + 2 < T) asm volatile("s_waitcnt vmcnt(6)" ::: "memory");
                else            asm volatile("s_waitcnt vmcnt(0)" ::: "memory");
                __builtin_amdgcn_sched_barrier(0);
                __builtin_amdgcn_s_barrier();
                __builtin_amdgcn_sched_barrier(0);
            }
        }

        const int crow = (lane >> 4) << 2;
        const int ccol = lane & 15;
        const long row0 = m_blk + ((long)(w >> 2) << 7);
        const long col0 = n_blk + ((w & 3) << 6);
#pragma unroll
        for (int mf = 0; mf < 8; ++mf) {
#pragma unroll
            for (int nf = 0; nf < 4; ++nf) {
                const long col = col0 + nf * 16 + ccol;
                const float bv = d.bias ? d.bias[col] : 0.f;
#pragma unroll
                for (int r = 0; r < 4; ++r) {
                    const long row = row0 + mf * 16 + crow + r;
                    const float v = acc[mf][nf][r] + bv;
                    if (d.c_fp32) ((float*)d.C)[row * (long)d.ldc + col] = v;
                    else ((bf16*)d.C)[row * (long)d.ldc + col] = __float2bfloat16(v);
                }
            }
        }
    }
}

// ---------------- pointwise ----------------
__device__ inline float sigf(float x) { return 1.f / (1.f + __expf(-x)); }
__device__ inline float tanh_fast(float x) { return 2.f / (1.f + __expf(-2.f * x)) - 1.f; }

__device__ inline void block_reduce4(float& a, float& b, float& c, float& d,
                                     float* s) {
#pragma unroll
    for (int off = 32; off > 0; off >>= 1) {
        a += __shfl_down(a, off, 64);
        b += __shfl_down(b, off, 64);
        c += __shfl_down(c, off, 64);
        d += __shfl_down(d, off, 64);
    }
    const int lane = threadIdx.x & 63, w = threadIdx.x >> 6;
    __syncthreads();
    if (lane == 0) { s[w] = a; s[w + 4] = b; s[w + 8] = c; s[w + 12] = d; }
    __syncthreads();
    a = s[0] + s[1] + s[2] + s[3];
    b = s[4] + s[5] + s[6] + s[7];
    c = s[8] + s[9] + s[10] + s[11];
    d = s[12] + s[13] + s[14] + s[15];
}

// Block handles sibling rows 2p,2p+1. Gates = sum over ns C-slices (csl elems
// apart); f-gate bias rows = sum over nsf fhb-slices (fsl apart).
__global__ __launch_bounds__(256) void pointwise_pair(
    const bf16* __restrict__ C, int ldc, int ns, long csl,
    const bf16* __restrict__ fhb, int nsf, long fsl,
    const bf16* __restrict__ hprev2,
    const float* __restrict__ x,
    const float* __restrict__ bfh,
    const float* __restrict__ gc, const float* __restrict__ bc,
    const float* __restrict__ gh, const float* __restrict__ bh,
    bf16* __restrict__ hout,
    bf16* __restrict__ Anext,
    int m0, int lp)
{
    __shared__ float sred[16];
    const int pl = blockIdx.x;
    const int t = threadIdx.x;
    const bool act = t < 192;
    const int j = t << 2;
    const bf16* cr0 = C + (long)(2 * pl) * ldc;
    const bf16* cr1 = cr0 + ldc;
    float c0v[4], c1v[4], h0v[4], h1v[4];
    float o0v[4] = {0, 0, 0, 0}, o1v[4] = {0, 0, 0, 0};
    float s0 = 0.f, q0 = 0.f, s1 = 0.f, q1 = 0.f;
    if (act) {
        float i0[4] = {0, 0, 0, 0}, i1[4] = {0, 0, 0, 0};
        float u0[4] = {0, 0, 0, 0}, u1[4] = {0, 0, 0, 0};
        float fx0[4] = {0, 0, 0, 0}, fx1[4] = {0, 0, 0, 0};
        float tv[4];
        for (int s = 0; s < ns; ++s) {
            const bf16* c0s = cr0 + (long)s * csl;
            const bf16* c1s = cr1 + (long)s * csl;
            ld4(c0s + j, tv);
#pragma unroll
            for (int q = 0; q < 4; q++) i0[q] += tv[q];
            ld4(c1s + j, tv);
#pragma unroll
            for (int q = 0; q < 4; q++) i1[q] += tv[q];
            ld4(c0s + Hdim + j, tv);
#pragma unroll
            for (int q = 0; q < 4; q++) o0v[q] += tv[q];
            ld4(c1s + Hdim + j, tv);
#pragma unroll
            for (int q = 0; q < 4; q++) o1v[q] += tv[q];
            ld4(c0s + 2 * Hdim + j, tv);
#pragma unroll
            for (int q = 0; q < 4; q++) u0[q] += tv[q];
            ld4(c1s + 2 * Hdim + j, tv);
#pragma unroll
            for (int q = 0; q < 4; q++) u1[q] += tv[q];
            if (fhb) {
                ld4(c0s + 3 * Hdim + j, tv);
#pragma unroll
                for (int q = 0; q < 4; q++) fx0[q] += tv[q];
                ld4(c1s + 3 * Hdim + j, tv);
#pragma unroll
                for (int q = 0; q < 4; q++) fx1[q] += tv[q];
            }
        }
        if (fhb) {
            float fb0[4] = {0, 0, 0, 0}, fb1[4] = {0, 0, 0, 0};
            float fb2[4] = {0, 0, 0, 0}, fb3[4] = {0, 0, 0, 0};
            const long base = (long)(4 * pl) * Hdim + j;
            for (int s = 0; s < nsf; ++s) {
                const bf16* fs = fhb + (long)s * fsl + base;
                ld4(fs, tv);
#pragma unroll
                for (int q = 0; q < 4; q++) fb0[q] += tv[q];
                ld4(fs + Hdim, tv);
#pragma unroll
                for (int q = 0; q < 4; q++) fb1[q] += tv[q];
                ld4(fs + 2 * Hdim, tv);
#pragma unroll
                for (int q = 0; q < 4; q++) fb2[q] += tv[q];
                ld4(fs + 3 * Hdim, tv);
#pragma unroll
                for (int q = 0; q < 4; q++) fb3[q] += tv[q];
            }
            float hp0[4], hp1[4], hp2[4], hp3[4];
            ld4(hprev2 + base, hp0); ld4(hprev2 + base + Hdim, hp1);
            ld4(hprev2 + base + 2 * Hdim, hp2); ld4(hprev2 + base + 3 * Hdim, hp3);
            const float4 bf4 = *(const float4*)(bfh + j);
#pragma unroll
            for (int q = 0; q < 4; q++) {
                const float bq = (&bf4.x)[q];
                float c0 = sigf(i0[q]) * tanh_fast(u0[q]);
                float c1 = sigf(i1[q]) * tanh_fast(u1[q]);
                c0 += sigf(fx0[q] + fb0[q] + bq) * hp0[q]
                    + sigf(fx0[q] + fb1[q] + bq) * hp1[q];
                c1 += sigf(fx1[q] + fb2[q] + bq) * hp2[q]
                    + sigf(fx1[q] + fb3[q] + bq) * hp3[q];
                c0v[q] = c0; c1v[q] = c1;
                s0 += c0; q0 += c0 * c0; s1 += c1; q1 += c1 * c1;
            }
        } else {
#pragma unroll
            for (int q = 0; q < 4; q++) {
                const float c0 = sigf(i0[q]) * tanh_fast(u0[q]);
                const float c1 = sigf(i1[q]) * tanh_fast(u1[q]);
                c0v[q] = c0; c1v[q] = c1;
                s0 += c0; q0 += c0 * c0; s1 += c1; q1 += c1 * c1;
            }
        }
    }
    block_reduce4(s0, q0, s1, q1, sred);
    const float m0c = s0 / Hdim, m1c = s1 / Hdim;
    const float r0c = rsqrtf(q0 / Hdim - m0c * m0c + 1e-5f);
    const float r1c = rsqrtf(q1 / Hdim - m1c * m1c + 1e-5f);
    float hs0 = 0.f, hq0 = 0.f, hs1 = 0.f, hq1 = 0.f;
    if (act) {
        const float4 gc4 = *(const float4*)(gc + j);
        const float4 bc4 = *(const float4*)(bc + j);
#pragma unroll
        for (int q = 0; q < 4; q++) {
            const float cn0 = (c0v[q] - m0c) * r0c * (&gc4.x)[q] + (&bc4.x)[q];
            const float cn1 = (c1v[q] - m1c) * r1c * (&gc4.x)[q] + (&bc4.x)[q];
            const float h0 = sigf(o0v[q]) * tanh_fast(cn0);
            const float h1 = sigf(o1v[q]) * tanh_fast(cn1);
            h0v[q] = h0; h1v[q] = h1;
            hs0 += h0; hq0 += h0 * h0; hs1 += h1; hq1 += h1 * h1;
        }
    }
    block_reduce4(hs0, hq0, hs1, hq1, sred);
    const float mh0 = hs0 / Hdim, mh1 = hs1 / Hdim;
    const float rh0 = rsqrtf(hq0 / Hdim - mh0 * mh0 + 1e-5f);
    const float rh1 = rsqrtf(hq1 / Hdim - mh1 * mh1 + 1e-5f);

    if (act) {
        const int pg = m0 / 2 + pl;
        const int b = pg >> lp;
        const int jn = pg & ((1 << lp) - 1);
        const float* xr = x + ((long)b * 255 + (1 << lp) - 1 + jn) * Hdim;
        bf16* arow = Anext + (long)pg * 1536;
        const float4 gh4 = *(const float4*)(gh + j);
        const float4 bh4 = *(const float4*)(bh + j);
        const float4 xr4 = *(const float4*)(xr + j);
        float hh0[4], hh1[4], ha[4], xs[4];
#pragma unroll
        for (int q = 0; q < 4; q++) {
            hh0[q] = (h0v[q] - mh0) * rh0 * (&gh4.x)[q] + (&bh4.x)[q];
            hh1[q] = (h1v[q] - mh1) * rh1 * (&gh4.x)[q] + (&bh4.x)[q];
            ha[q] = hh0[q] + hh1[q];
            xs[q] = (&xr4.x)[q];
        }
        st4(hout + (long)(2 * pl) * Hdim + j, hh0);
        st4(hout + (long)(2 * pl + 1) * Hdim + j, hh1);
        st4(arow + 768 + j, ha);
        st4(arow + j, xs);
    }
}

__global__ __launch_bounds__(256) void pointwise_root(
    const bf16* __restrict__ C, int ldc, int ns, long csl,
    const bf16* __restrict__ fhb, int nsf, long fsl,
    const bf16* __restrict__ hprev,
    const float* __restrict__ bfh,
    const float* __restrict__ gc, const float* __restrict__ bc,
    const float* __restrict__ gh, const float* __restrict__ bh,
    bf16* __restrict__ hout)
{
    __shared__ float sred[16];
    const int m = blockIdx.x;
    const int t = threadIdx.x;
    const bool act = t < 192;
    const int j = t << 2;
    const bf16* cr = C + (long)m * ldc;
    float cv[4], hv[4];
    float ov[4] = {0, 0, 0, 0};
    float ssum = 0.f, ssq = 0.f, d0 = 0.f, d1 = 0.f;
    if (act) {
        float iv[4] = {0, 0, 0, 0}, uv[4] = {0, 0, 0, 0}, fx[4] = {0, 0, 0, 0};
        float tv[4];
        for (int s = 0; s < ns; ++s) {
            const bf16* cs = cr + (long)s * csl;
            ld4(cs + j, tv);
#pragma unroll
            for (int q = 0; q < 4; q++) iv[q] += tv[q];
            ld4(cs + Hdim + j, tv);
#pragma unroll
            for (int q = 0; q < 4; q++) ov[q] += tv[q];
            ld4(cs + 2 * Hdim + j, tv);
#pragma unroll
            for (int q = 0; q < 4; q++) uv[q] += tv[q];
            ld4(cs + 3 * Hdim + j, tv);
#pragma unroll
            for (int q = 0; q < 4; q++) fx[q] += tv[q];
        }
        float fb0[4] = {0, 0, 0, 0}, fb1[4] = {0, 0, 0, 0};
        const long base = (long)(2 * m) * Hdim + j;
        for (int s = 0; s < nsf; ++s) {
            const bf16* fs = fhb + (long)s * fsl + base;
            ld4(fs, tv);
#pragma unroll
            for (int q = 0; q < 4; q++) fb0[q] += tv[q];
            ld4(fs + Hdim, tv);
#pragma unroll
            for (int q = 0; q < 4; q++) fb1[q] += tv[q];
        }
        float hp0[4], hp1[4];
        ld4(hprev + base, hp0); ld4(hprev + base + Hdim, hp1);
        const float4 bf4 = *(const float4*)(bfh + j);
#pragma unroll
        for (int q = 0; q < 4; q++) {
            const float bq = (&bf4.x)[q];
            float c = sigf(iv[q]) * tanh_fast(uv[q]);
            c += sigf(fx[q] + fb0[q] + bq) * hp0[q]
               + sigf(fx[q] + fb1[q] + bq) * hp1[q];
            cv[q] = c; ssum += c; ssq += c * c;
        }
    }
    block_reduce4(ssum, ssq, d0, d1, sred);
    const float mean = ssum / Hdim;
    const float rstd = rsqrtf(ssq / Hdim - mean * mean + 1e-5f);
    float hs = 0.f, hq = 0.f;
    if (act) {
        const float4 gc4 = *(const float4*)(gc + j);
        const float4 bc4 = *(const float4*)(bc + j);
#pragma unroll
        for (int q = 0; q < 4; q++) {
            const float cn = (cv[q] - mean) * rstd * (&gc4.x)[q] + (&bc4.x)[q];
            const float h = sigf(ov[q]) * tanh_fast(cn);
            hv[q] = h; hs += h; hq += h * h;
        }
    }
    d0 = 0.f; d1 = 0.f;
    block_reduce4(hs, hq, d0, d1, sred);
    const float mh = hs / Hdim;
    const float rh = rsqrtf(hq / Hdim - mh * mh + 1e-5f);
    if (act) {
        const float4 gh4 = *(const float4*)(gh + j);
        const float4 bh4 = *(const float4*)(bh + j);
        float hh[4];
#pragma unroll
        for (int q = 0; q < 4; q++)
            hh[q] = (hv[q] - mh) * rh * (&gh4.x)[q] + (&bh4.x)[q];
        st4(hout + (long)m * Hdim + j, hh);
    }
}

// out = sum_s P[s] + b_out + x[:,0]
__global__ __launch_bounds__(192) void out_reduce(
    const float* __restrict__ P, long psl, int ns,
    const float* __restrict__ b_out, const float* __restrict__ x,
    float* __restrict__ out)
{
    const int m = blockIdx.x;
    const int j = threadIdx.x << 2;
    float4 a = *(const float4*)(b_out + j);
    const float4 xv = *(const float4*)(x + (long)m * 255 * 768 + j);
    a.x += xv.x; a.y += xv.y; a.z += xv.z; a.w += xv.w;
    for (int s = 0; s < ns; ++s) {
        const float4 pv = *(const float4*)(P + (long)s * psl + (long)m * 768 + j);
        a.x += pv.x; a.y += pv.y; a.z += pv.z; a.w += pv.w;
    }
    *(float4*)(out + (long)m * 768 + j) = a;
}

// ---------------- launch ----------------
extern "C" void kernel_launch(void* const* d_in, const int* in_sizes, int n_in,
                              void* d_out, int out_size, void* d_ws, size_t ws_size,
                              hipStream_t stream) {
    (void)in_sizes; (void)n_in; (void)out_size; (void)ws_size;
    const float* x      = (const float*)d_in[0];
    const float* Wioux  = (const float*)d_in[1];
    const float* b_ioux = (const float*)d_in[2];
    const float* Wiouh  = (const float*)d_in[3];
    const float* Wfx    = (const float*)d_in[4];
    const float* b_fx   = (const float*)d_in[5];
    const float* Wfh    = (const float*)d_in[6];
    const float* b_fh   = (const float*)d_in[7];
    const float* ln_c_g = (const float*)d_in[8];
    const float* ln_c_b = (const float*)d_in[9];
    const float* ln_h_g = (const float*)d_in[10];
    const float* ln_h_b = (const float*)d_in[11];
    const float* Wout   = (const float*)d_in[12];
    const float* b_out  = (const float*)d_in[13];
    float* out = (float*)d_out;

    // ---- workspace (~214 MB) ----
    char* p = (char*)d_ws;
    bf16* W_cat   = (bf16*)p; p += 8L * 3072 * 1536 * 2;   // 75.5 MB
    bf16* Wfh_bf  = (bf16*)p; p += 8L * 768 * 768 * 2;     //  9.4 MB
    bf16* Wout_bf = (bf16*)p; p += 768L * 768 * 2;         //  1.2 MB
    float* b_cat  = (float*)p; p += 8L * 3072 * 4;         //  0.1 MB
    bf16* leafA   = (bf16*)p; p += 16384L * 768 * 2;       // 25.2 MB (fhb overlay)
    bf16* A6      = (bf16*)p; p += 8192L * 1536 * 2;       // 25.2 MB
    bf16* A5      = (bf16*)p; p += 4096L * 1536 * 2;       // 12.6 MB
    bf16* Cbuf    = (bf16*)p; p += 4096L * 3072 * 2;       // 25.2 MB
    bf16* hA      = (bf16*)p; p += 16384L * 768 * 2;       // 25.2 MB
    bf16* hB      = (bf16*)p; p += 8192L * 768 * 2;        // 12.6 MB
    unsigned int* ctrs = (unsigned int*)p; p += 64;        // job counters
    float* outP   = (float*)p; p += 128L * 768 * 4 * 4;    //  1.6 MB (out partials)
    bf16* fhb     = leafA;  // leafA dead once leaf GEMMs complete
    bf16* Cleaf   = A5;     // A5+Cbuf contiguous = 8192*2304*2 bytes capacity

    // ---- prep (2 launches; prep_misc also zeroes job counters) ----
    conv_wcat<<<8 * 3072, 384, 0, stream>>>(Wioux, Wiouh, Wfx, W_cat);
    prep_misc<<<5280 + 16384 + 1, 256, 0, stream>>>(
        Wfh, Wout, b_ioux, b_fx, x, Wfh_bf, Wout_bf, b_cat, leafA, ctrs);

    GemmDesc dummy = mkdesc(nullptr, 0, nullptr, 0, nullptr, nullptr, 0, 0, 0, 1,
                            nullptr, 0, 1, 0);
    int kc = 0;   // counter index

    // ---- leaf level l=7: 3 chunks, persistent 256^2 kernel ----
    {
        const int cm0[3] = {0, 5632, 11264};
        const int cmc[3] = {5632, 5632, 5120};
        for (int c = 0; c < 3; c++) {
            const int m0 = cm0[c], Mc = cmc[c];
            GemmDesc dl = mkdesc(leafA + (long)m0 * 768, 768,
                                 W_cat + 7L * 3072 * 1536, 1536, b_cat + 7 * 3072,
                                 Cleaf, 2304, 0, 768, 9, nullptr, 0,
                                 (Mc / 256) * 9, 0);
            const int ntot = (Mc / 256) * 9;
            gemm8_dual<<<(ntot < 256 ? ntot : 256), 512, 0, stream>>>(
                dl, ntot, dummy, ntot, ctrs + kc++);
            pointwise_pair<<<Mc / 2, 256, 0, stream>>>(
                Cleaf, 2304, 1, 0, nullptr, 1, 0, nullptr, x, nullptr,
                ln_c_g + 7 * Hdim, ln_c_b + 7 * Hdim, ln_h_g + 7 * Hdim, ln_h_b + 7 * Hdim,
                hA + (long)m0 * Hdim, A6, m0, 6);
        }
    }

    bf16* hp = hA; bf16* hc = hB;
    bf16* Acur = A6; bf16* Anxt = A5;

    // ---- levels 6..5: persistent 256^2 kernel, chunks of 4096 rows ----
    for (int l = 6; l >= 5; l--) {
        const int M = 128 << l;
        const int Mc = 4096;
        const int nch = M / Mc;
        for (int c = 0; c < nch; c++) {
            const int m0 = c * Mc;
            GemmDesc diou = mkdesc(Acur + (long)m0 * 1536, 1536,
                                   W_cat + (long)l * 3072 * 1536, 1536,
                                   b_cat + l * 3072, Cbuf, 3072, 0, 1536, 12,
                                   nullptr, 0, 12 * (Mc / 256), 0);
            GemmDesc dfh = mkdesc(hp + (long)2 * m0 * Hdim, 768,
                                  Wfh_bf + (long)l * 768 * 768, 768, nullptr,
                                  fhb, 768, 0, 768, 3, nullptr, 0,
                                  3 * (2 * Mc / 256), 0);
            const int na = 12 * (Mc / 256);
            const int nb = 3 * (2 * Mc / 256);
            const int ntot = na + nb;
            gemm8_dual<<<(ntot < 256 ? ntot : 256), 512, 0, stream>>>(
                diou, na, dfh, ntot, ctrs + kc++);
            pointwise_pair<<<Mc / 2, 256, 0, stream>>>(
                Cbuf, 3072, 1, 0, fhb, 1, 0, hp + (long)2 * m0 * Hdim,
                x, b_fh + l * Hdim,
                ln_c_g + l * Hdim, ln_c_b + l * Hdim, ln_h_g + l * Hdim, ln_h_b + l * Hdim,
                hc + (long)m0 * Hdim, Anxt, m0, l - 1);
        }
        bf16* t1 = hp; hp = hc; hc = t1;
        bf16* t2 = Acur; Acur = Anxt; Anxt = t2;
    }

    // ---- levels 4..1: split-K 128^2 gemm_dual (latency fix) ----
    for (int l = 4; l >= 1; l--) {
        const int M = 128 << l;                 // 2048,1024,512,256
        const int Si = (l == 4) ? 2 : 4;        // iou K-slices (capacity-bound at l4)
        const int Sf = (l == 4) ? 2 : 4;        // fh K-slices
        const int Ki = 1536 / Si;
        const int Kf = 768 / Sf;
        const int npsA = (M / 128) * 24;
        const int npsB = (2 * M / 128) * 6;
        GemmDesc diou = mkdesc(Acur, 1536,
                               W_cat + (long)l * 3072 * 1536, 1536,
                               b_cat + l * 3072, Cbuf, 3072, 0, Ki, 24,
                               nullptr, 0, npsA, (long)M * 3072 * 2);
        GemmDesc dfh = mkdesc(hp, 768,
                              Wfh_bf + (long)l * 768 * 768, 768, nullptr,
                              fhb, 768, 0, Kf, 6,
                              nullptr, 0, npsB, (long)2 * M * 768 * 2);
        const int na = Si * npsA;
        const int nb = Sf * npsB;
        gemm_dual<<<na + nb, 256, 0, stream>>>(diou, na, dfh);
        pointwise_pair<<<M / 2, 256, 0, stream>>>(
            Cbuf, 3072, Si, (long)M * 3072, fhb, Sf, (long)2 * M * 768,
            hp, x, b_fh + l * Hdim,
            ln_c_g + l * Hdim, ln_c_b + l * Hdim, ln_h_g + l * Hdim, ln_h_b + l * Hdim,
            hc, Anxt, 0, l - 1);
        bf16* t1 = hp; hp = hc; hc = t1;
        bf16* t2 = Acur; Acur = Anxt; Anxt = t2;
    }

    // ---- root level l=0 (M=128): split-K S_iou=4, S_fh=2 ----
    {
        GemmDesc diou = mkdesc(Acur, 1536, W_cat, 1536, b_cat, Cbuf, 3072, 0,
                               384, 24, nullptr, 0, 24, 128L * 3072 * 2);
        GemmDesc dfh = mkdesc(hp, 768, Wfh_bf, 768, nullptr, fhb, 768, 0,
                              384, 6, nullptr, 0, 12, 256L * 768 * 2);
        const int na = 4 * 24, nb = 2 * 12;
        gemm_dual<<<na + nb, 256, 0, stream>>>(diou, na, dfh);
        pointwise_root<<<128, 256, 0, stream>>>(
            Cbuf, 3072, 4, 128L * 3072, fhb, 2, 256L * 768, hp, b_fh,
            ln_c_g, ln_c_b, ln_h_g, ln_h_b, hc);
    }

    // ---- out = h_root @ Wout^T + b_out + x[:,0]: split-K S=4, fp32 partials ----
    {
        GemmDesc dout = mkdesc(hc, 768, Wout_bf, 768, nullptr, outP, 768, 1,
                               192, 6, nullptr, 0, 6, 128L * 768 * 4);
        gemm_dual<<<4 * 6, 256, 0, stream>>>(dout, 4 * 6, dummy);
        out_reduce<<<128, 192, 0, stream>>>(outP, 128L * 768, 4, b_out, x, out);
    }
}